// Round 2
// baseline (690.268 us; speedup 1.0000x reference)
//
#include <hip/hip_runtime.h>
#include <hip/hip_bf16.h>
#include <stdint.h>

// Problem constants (fixed by the reference)
#define BB 2
#define NSEQ 2048
#define DM 1024
#define H 16
#define HD 128
#define D1 2048
#define NKI 16
#define RANKI 32
#define MROWS (BB * NSEQ)   // 4096 rows for all GEMMs
#define KTROWS (2 * NSEQ)   // 4096 lag-table rows (index = lag + 2048)

typedef short short8 __attribute__((ext_vector_type(8)));
typedef float floatx4 __attribute__((ext_vector_type(4)));

__device__ __forceinline__ float bf2f(unsigned short u) {
  union { unsigned int i; float f; } v; v.i = ((unsigned int)u) << 16; return v.f;
}
__device__ __forceinline__ unsigned short f2bf(float f) {
  union { float f; unsigned int i; } v; v.f = f;
  unsigned int r = (v.i + 0x7FFFu + ((v.i >> 16) & 1u)) >> 16;
  return (unsigned short)r;
}

// ---------------- fp32 -> bf16 elementwise convert (vectorized) ------------
__global__ __launch_bounds__(256) void cvt_kernel(const float* __restrict__ in,
                                                  unsigned short* __restrict__ out,
                                                  int n4) {
  int i = blockIdx.x * 256 + threadIdx.x;
  if (i >= n4) return;
  float4 f = ((const float4*)in)[i];
  ushort4 o;
  o.x = f2bf(f.x); o.y = f2bf(f.y); o.z = f2bf(f.z); o.w = f2bf(f.w);
  ((ushort4*)out)[i] = o;
}

// ------- fused transpose+convert: out_bf16[c][r] = in_f32[r][c] ------------
__global__ __launch_bounds__(256) void tpc_kernel(const float* __restrict__ in,
                                                  unsigned short* __restrict__ out,
                                                  int rows, int cols) {
  __shared__ unsigned short t[32][33];
  int bx = blockIdx.x * 32, by = blockIdx.y * 32;
  int tx = threadIdx.x, ty = threadIdx.y; // blockDim = (32,8)
#pragma unroll
  for (int j = 0; j < 32; j += 8)
    t[ty + j][tx] = f2bf(in[(size_t)(by + ty + j) * cols + bx + tx]);
  __syncthreads();
#pragma unroll
  for (int j = 0; j < 32; j += 8)
    out[(size_t)(bx + ty + j) * rows + by + tx] = t[tx][ty + j];
}

// ---------------- k_ind = a @ b per head:  [H][NK][HD] fp32 ----------------
__global__ __launch_bounds__(256) void kind_kernel(const float* __restrict__ a,
                                                   const float* __restrict__ b,
                                                   float* __restrict__ kout) {
  int h = blockIdx.x;
  for (int e = threadIdx.x; e < NKI * HD; e += 256) {
    int k = e >> 7, d = e & 127;
    float s = 0.0f;
#pragma unroll
    for (int r = 0; r < RANKI; ++r)
      s += a[(h * NKI + k) * RANKI + r] * b[(h * RANKI + r) * HD + d];
    kout[(h * NKI + k) * HD + d] = s;
  }
}

// ---------------- full lag table Kt[h][lag+2048][d], bf16 ------------------
__global__ __launch_bounds__(256) void ktable_kernel(const float* __restrict__ kip,
                                                     const float* __restrict__ kin,
                                                     const float* __restrict__ tz,
                                                     unsigned short* __restrict__ Kt) {
  int h = blockIdx.y;
  int i0 = blockIdx.x * 256;
  for (int e = threadIdx.x; e < 256 * 128; e += 256) {
    int il = e >> 7, d = e & 127;
    int i = i0 + il;
    int lag = i - NSEQ;
    float val;
    if (i == 0) {
      val = 0.0f;                       // lag -2048: never referenced, keep defined
    } else if (lag == 0) {
      val = tz[h * HD + d];
    } else {
      int l = lag > 0 ? lag : -lag;
      const float* src = lag > 0 ? kip : kin;
      float p = (float)(l - 1) * (15.0f / 2046.0f);
      int lo = (int)p;                  // p >= 0
      int hi = lo + 1; if (hi > 15) hi = 15;
      if (lo > 15) lo = 15;
      float w = p - (float)lo;
      float kv = src[(h * NKI + lo) * HD + d] * (1.0f - w)
               + src[(h * NKI + hi) * HD + d] * w;
      val = kv * __powf(0.999f, (float)l);
    }
    Kt[((size_t)h * KTROWS + i) * HD + d] = f2bf(val);
  }
}

// ---------------- bf16 MFMA GEMM: C = [silu](A @ Bt^T + bias) --------------
// A: [M][K] row-major bf16; Bt: [N][K] row-major bf16 (pre-transposed W);
// bias fp32; C bf16 or fp32. 64x64 tile, 4 waves, each wave a 32x32 quadrant.
__global__ __launch_bounds__(256) void gemm_bf16(const unsigned short* __restrict__ A,
                                                 const unsigned short* __restrict__ Bt,
                                                 const float* __restrict__ bias,
                                                 void* __restrict__ C,
                                                 int M, int N, int K,
                                                 int do_silu, int c_fp32) {
  __shared__ unsigned short Al[64 * 40];   // pad 32 -> 40 (80B row)
  __shared__ unsigned short Bl[64 * 40];
  int m0 = blockIdx.y * 64, n0 = blockIdx.x * 64;
  int tid = threadIdx.x;
  int lane = tid & 63, w = tid >> 6;
  int rw = (w >> 1) * 32, cw = (w & 1) * 32;
  int q = lane >> 4, l16 = lane & 15;
  floatx4 acc00 = {0.f,0.f,0.f,0.f}, acc01 = {0.f,0.f,0.f,0.f};
  floatx4 acc10 = {0.f,0.f,0.f,0.f}, acc11 = {0.f,0.f,0.f,0.f};
  int sr = tid >> 2, sk = (tid & 3) * 8;
  for (int k0 = 0; k0 < K; k0 += 32) {
    __syncthreads();
    *(uint4*)(&Al[sr * 40 + sk]) = *(const uint4*)(A + (size_t)(m0 + sr) * K + k0 + sk);
    *(uint4*)(&Bl[sr * 40 + sk]) = *(const uint4*)(Bt + (size_t)(n0 + sr) * K + k0 + sk);
    __syncthreads();
    // a-frag: A[m = lane&15][k = q*8 + j]; b-frag: B[k = q*8 + j][n = lane&15]
    short8 a0 = *(const short8*)(&Al[(rw + l16) * 40 + q * 8]);
    short8 a1 = *(const short8*)(&Al[(rw + 16 + l16) * 40 + q * 8]);
    short8 b0 = *(const short8*)(&Bl[(cw + l16) * 40 + q * 8]);
    short8 b1 = *(const short8*)(&Bl[(cw + 16 + l16) * 40 + q * 8]);
    acc00 = __builtin_amdgcn_mfma_f32_16x16x32_bf16(a0, b0, acc00, 0, 0, 0);
    acc01 = __builtin_amdgcn_mfma_f32_16x16x32_bf16(a0, b1, acc01, 0, 0, 0);
    acc10 = __builtin_amdgcn_mfma_f32_16x16x32_bf16(a1, b0, acc10, 0, 0, 0);
    acc11 = __builtin_amdgcn_mfma_f32_16x16x32_bf16(a1, b1, acc11, 0, 0, 0);
  }
  // epilogue: D[row = q*4 + r][col = lane&15] per 16x16 tile (verified mapping)
  floatx4 accs[2][2] = {{acc00, acc01}, {acc10, acc11}};
#pragma unroll
  for (int mt = 0; mt < 2; ++mt) {
#pragma unroll
    for (int nt = 0; nt < 2; ++nt) {
      int n = n0 + cw + nt * 16 + l16;
      float bsv = bias[n];
#pragma unroll
      for (int r = 0; r < 4; ++r) {
        int m = m0 + rw + mt * 16 + q * 4 + r;
        float val = accs[mt][nt][r] + bsv;
        if (do_silu) val = val / (1.0f + __expf(-val));
        if (c_fp32) ((float*)C)[(size_t)m * N + n] = val;
        else ((unsigned short*)C)[(size_t)m * N + n] = f2bf(val);
      }
    }
  }
}

// ---------------- direct Toeplitz conv + gate ------------------------------
// y[b,t,h,d] = sum_s v[b,s,h,d] * Kt[h][t-s+2048][d];  g = u * y (bf16).
// G may alias U: each element is read-then-written by the same thread.
// grid (NSEQ/64, H, BB), 256 threads: d = tid&127, grp = tid>>7 (32 t's each).
// 32-deep rotating K register window; (t0-s0) % 32 == 0 keeps indices static.
__global__ __launch_bounds__(256) void conv_kernel(const unsigned short* __restrict__ V,
                                                   const unsigned short* __restrict__ Kt,
                                                   const unsigned short* __restrict__ U,
                                                   unsigned short* __restrict__ G) {
  __shared__ unsigned short Vl[32 * 128];  // 8 KB
  __shared__ unsigned short Kl[64 * 128];  // 16 KB
  int t0 = blockIdx.x * 64, h = blockIdx.y, b = blockIdx.z;
  int tid = threadIdx.x;
  int d = tid & 127, grp = tid >> 7;
  int tbase = t0 + grp * 32;
  const unsigned short* Vb = V + ((size_t)b * NSEQ) * D1 + h * HD;
  const unsigned short* Kh = Kt + (size_t)h * KTROWS * HD;
  float acc[32];
#pragma unroll
  for (int i = 0; i < 32; ++i) acc[i] = 0.0f;
  // preload window: slot i holds lag-row (tbase + i)  (for s0 = 0, sl = 0)
  float kreg[32];
  {
    const unsigned short* Kg = Kh + (size_t)(tbase + NSEQ) * HD + d;
#pragma unroll
    for (int i = 0; i < 32; ++i) kreg[i] = bf2f(Kg[(size_t)i * HD]);
  }
  int srow = tid >> 3, scol = (tid & 7) * 16;
  for (int s0 = 0; s0 < NSEQ; s0 += 32) {
    __syncthreads();
    { // stage V rows s0..s0+31
      const unsigned short* src = Vb + (size_t)(s0 + srow) * D1 + scol;
      *(uint4*)(&Vl[srow * 128 + scol]) = *(const uint4*)(src);
      *(uint4*)(&Vl[srow * 128 + scol + 8]) = *(const uint4*)(src + 8);
    }
    { // stage K rows [t0-s0-32+2048, t0-s0+31+2048]  (rows entering the windows)
      int kbase = t0 - s0 - 32 + NSEQ;
#pragma unroll
      for (int j = 0; j < 64; j += 32) {
        const unsigned short* src = Kh + (size_t)(kbase + srow + j) * HD + scol;
        *(uint4*)(&Kl[(srow + j) * 128 + scol]) = *(const uint4*)(src);
        *(uint4*)(&Kl[(srow + j) * 128 + scol + 8]) = *(const uint4*)(src + 8);
      }
    }
    __syncthreads();
    int klbase = grp * 32;
#pragma unroll
    for (int sl = 0; sl < 32; ++sl) {
      float vs = bf2f(Vl[sl * 128 + d]);
#pragma unroll
      for (int i = 0; i < 32; ++i) acc[i] += kreg[(i - sl) & 31] * vs;
      // load lag-row (tbase - s0 - sl - 1) into slot (-(sl+1))&31 = 31-sl
      kreg[31 - sl] = bf2f(Kl[(klbase + 31 - sl) * 128 + d]);
    }
  }
  size_t base = ((size_t)b * NSEQ + tbase) * D1 + h * HD + d;
#pragma unroll
  for (int i = 0; i < 32; ++i) {
    float uu = bf2f(U[base + (size_t)i * D1]);
    G[base + (size_t)i * D1] = f2bf(uu * acc[i]);
  }
}

// ---------------------------------------------------------------------------
extern "C" void kernel_launch(void* const* d_in, const int* in_sizes, int n_in,
                              void* d_out, int out_size, void* d_ws, size_t ws_size,
                              hipStream_t stream) {
  // Reference dtypes are all float32.
  const float* x      = (const float*)d_in[0];
  const float* Wu     = (const float*)d_in[1];
  const float* bu     = (const float*)d_in[2];
  const float* Wv     = (const float*)d_in[3];
  const float* bv     = (const float*)d_in[4];
  const float* Wo     = (const float*)d_in[5];
  const float* bo     = (const float*)d_in[6];
  const float* a_pos  = (const float*)d_in[7];
  const float* b_pos  = (const float*)d_in[8];
  const float* a_neg  = (const float*)d_in[9];
  const float* b_neg  = (const float*)d_in[10];
  const float* t_zero = (const float*)d_in[11];
  float* out = (float*)d_out;

  char* ws = (char*)d_ws;
  unsigned short* x_bf  = (unsigned short*)ws; ws += (size_t)MROWS * DM * 2;       //  8 MB
  unsigned short* u_ws  = (unsigned short*)ws; ws += (size_t)MROWS * D1 * 2;       // 16 MB (g aliases)
  unsigned short* v_ws  = (unsigned short*)ws; ws += (size_t)MROWS * D1 * 2;       // 16 MB
  unsigned short* Kt_ws = (unsigned short*)ws; ws += (size_t)H * KTROWS * HD * 2;  // 16 MB
  unsigned short* WuT   = (unsigned short*)ws; ws += (size_t)D1 * DM * 2;          //  4 MB
  unsigned short* WvT   = (unsigned short*)ws; ws += (size_t)D1 * DM * 2;          //  4 MB
  unsigned short* WoT   = (unsigned short*)ws; ws += (size_t)DM * D1 * 2;          //  4 MB
  float* kip = (float*)ws; ws += (size_t)H * NKI * HD * 4;                          // 128 KB
  float* kin = (float*)ws; ws += (size_t)H * NKI * HD * 4;                          // 128 KB

  dim3 tb256(256);
  dim3 tptb(32, 8);
  // x -> bf16
  cvt_kernel<<<dim3((MROWS * DM / 4 + 255) / 256), tb256, 0, stream>>>(x, x_bf, MROWS * DM / 4);
  // weight transpose+convert (coalesced B-operand staging for the GEMMs)
  tpc_kernel<<<dim3(D1 / 32, DM / 32), tptb, 0, stream>>>(Wu, WuT, DM, D1);
  tpc_kernel<<<dim3(D1 / 32, DM / 32), tptb, 0, stream>>>(Wv, WvT, DM, D1);
  tpc_kernel<<<dim3(DM / 32, D1 / 32), tptb, 0, stream>>>(Wo, WoT, D1, DM);
  // kernel table
  kind_kernel<<<dim3(H), tb256, 0, stream>>>(a_pos, b_pos, kip);
  kind_kernel<<<dim3(H), tb256, 0, stream>>>(a_neg, b_neg, kin);
  ktable_kernel<<<dim3(KTROWS / 256, H), tb256, 0, stream>>>(kip, kin, t_zero, Kt_ws);
  // u = silu(x@Wu+bu), v = silu(x@Wv+bv)
  gemm_bf16<<<dim3(D1 / 64, MROWS / 64), tb256, 0, stream>>>(x_bf, WuT, bu, u_ws, MROWS, D1, DM, 1, 0);
  gemm_bf16<<<dim3(D1 / 64, MROWS / 64), tb256, 0, stream>>>(x_bf, WvT, bv, v_ws, MROWS, D1, DM, 1, 0);
  // g = u * toeplitz_conv(v, Kt)   (written in-place over u_ws)
  conv_kernel<<<dim3(NSEQ / 64, H, BB), tb256, 0, stream>>>(v_ws, Kt_ws, u_ws, u_ws);
  // out = g @ Wo + bo  (fp32 store)
  gemm_bf16<<<dim3(DM / 64, MROWS / 64), tb256, 0, stream>>>(u_ws, WoT, bo, out, MROWS, DM, D1, 0, 1);
}

// Round 5
// 384.438 us; speedup vs baseline: 1.7955x; 1.7955x over previous
//
#include <hip/hip_runtime.h>
#include <hip/hip_bf16.h>
#include <stdint.h>
#include <stddef.h>

// Problem constants (fixed by the reference)
#define BB 2
#define NSEQ 2048
#define DM 1024
#define H 16
#define HD 128
#define D1 2048
#define NKI 16
#define RANKI 32
#define MROWS (BB * NSEQ)   // 4096 rows for all GEMMs
#define VPROWS 6144         // 2048 zero-pad | 2048 data | 2048 zero-pad
#define NTAP 28
#define NCHUNK 32
#define CLEN 64
#define GAMMA_F 0.999f
// ln(0.999), for gamma^x = exp(x*ln_g)  (__exp2f collides with glibc; __expf is safe)
#define LN_G (-1.00050033e-3f)

// Sparse-tap positions of delta = (1 - g z)^2 * K  (K piecewise-linear * g^l,
// knots at l = 1 + 136.4j; integer knots j=5 (683), j=10 (1365) give 1 tap).
// __device__ so runtime-indexed access from kernels is legal.
__device__ constexpr int TAPS[NTAP] = {
  1, 2, 138, 139, 274, 275, 411, 412, 547, 548, 684,
  820, 821, 956, 957, 1093, 1094, 1229, 1230, 1366,
  1502, 1503, 1638, 1639, 1775, 1776, 1911, 1912};

typedef short short8 __attribute__((ext_vector_type(8)));
typedef float floatx4 __attribute__((ext_vector_type(4)));

__device__ __forceinline__ float bf2f(unsigned short u) {
  union { unsigned int i; float f; } v; v.i = ((unsigned int)u) << 16; return v.f;
}
__device__ __forceinline__ unsigned short f2bf(float f) {
  union { float f; unsigned int i; } v; v.f = f;
  unsigned int r = (v.i + 0x7FFFu + ((v.i >> 16) & 1u)) >> 16;
  return (unsigned short)r;
}

// ---------------- fp32 -> bf16 elementwise convert (vectorized) ------------
__global__ __launch_bounds__(256) void cvt_kernel(const float* __restrict__ in,
                                                  unsigned short* __restrict__ out,
                                                  int n4) {
  int i = blockIdx.x * 256 + threadIdx.x;
  if (i >= n4) return;
  float4 f = ((const float4*)in)[i];
  ushort4 o;
  o.x = f2bf(f.x); o.y = f2bf(f.y); o.z = f2bf(f.z); o.w = f2bf(f.w);
  ((ushort4*)out)[i] = o;
}

// ------- fused transpose+convert: out_bf16[c][r] = in_f32[r][c] ------------
__global__ __launch_bounds__(256) void tpc_kernel(const float* __restrict__ in,
                                                  unsigned short* __restrict__ out,
                                                  int rows, int cols) {
  __shared__ unsigned short t[32][33];
  int bx = blockIdx.x * 32, by = blockIdx.y * 32;
  int tx = threadIdx.x, ty = threadIdx.y; // blockDim = (32,8)
#pragma unroll
  for (int j = 0; j < 32; j += 8)
    t[ty + j][tx] = f2bf(in[(size_t)(by + ty + j) * cols + bx + tx]);
  __syncthreads();
#pragma unroll
  for (int j = 0; j < 32; j += 8)
    out[(size_t)(bx + ty + j) * rows + by + tx] = t[tx][ty + j];
}

// ---------------- k_ind = a @ b per head:  [H][NK][HD] fp32 ----------------
__global__ __launch_bounds__(256) void kind_kernel(const float* __restrict__ a,
                                                   const float* __restrict__ b,
                                                   float* __restrict__ kout) {
  int h = blockIdx.x;
  for (int e = threadIdx.x; e < NKI * HD; e += 256) {
    int k = e >> 7, d = e & 127;
    float s = 0.0f;
#pragma unroll
    for (int r = 0; r < RANKI; ++r)
      s += a[(h * NKI + k) * RANKI + r] * b[(h * RANKI + r) * HD + d];
    kout[(h * NKI + k) * HD + d] = s;
  }
}

// ---- K(l) = interp(kind, l) * gamma^l  (same formula as the direct ref) ---
__device__ __forceinline__ float Kinterp(const float* __restrict__ kk, int l, int d) {
  if (l < 1) return 0.0f;   // l > 2047 never queried (max tap 1912)
  float p = (float)(l - 1) * (15.0f / 2046.0f);
  int lo = (int)p; if (lo > 15) lo = 15;
  int hi = lo + 1; if (hi > 15) hi = 15;
  float w = p - (float)lo;
  float v = kk[lo * HD + d] * (1.0f - w) + kk[hi * HD + d] * w;
  return v * __powf(GAMMA_F, (float)l);
}

// ---------------- delta table: dtab[h][j][d] = (1-gz)^2 K at tap l_j -------
__global__ __launch_bounds__(256) void dtab_kernel(const float* __restrict__ kind,
                                                   float* __restrict__ dtab) {
  int h = blockIdx.x;
  const float* kk = kind + h * NKI * HD;
  for (int e = threadIdx.x; e < NTAP * HD; e += 256) {
    int j = e >> 7, d = e & 127;
    int l = TAPS[j];
    float K0 = Kinterp(kk, l, d);
    float K1 = Kinterp(kk, l - 1, d);
    float K2 = Kinterp(kk, l - 2, d);
    dtab[(h * NTAP + j) * HD + d] = K0 - 2.0f * GAMMA_F * K1 + (GAMMA_F * GAMMA_F) * K2;
  }
}

// ---------------- bf16 MFMA GEMM: C = [silu](A @ Bt^T + bias) --------------
// row_remap: write into zero-padded V layout (row = 2048 + t + b*6144).
__global__ __launch_bounds__(256) void gemm_bf16(const unsigned short* __restrict__ A,
                                                 const unsigned short* __restrict__ Bt,
                                                 const float* __restrict__ bias,
                                                 void* __restrict__ C,
                                                 int M, int N, int K,
                                                 int do_silu, int c_fp32, int row_remap) {
  __shared__ unsigned short Al[64 * 40];
  __shared__ unsigned short Bl[64 * 40];
  int m0 = blockIdx.y * 64, n0 = blockIdx.x * 64;
  int tid = threadIdx.x;
  int lane = tid & 63, w = tid >> 6;
  int rw = (w >> 1) * 32, cw = (w & 1) * 32;
  int q = lane >> 4, l16 = lane & 15;
  floatx4 acc00 = {0.f,0.f,0.f,0.f}, acc01 = {0.f,0.f,0.f,0.f};
  floatx4 acc10 = {0.f,0.f,0.f,0.f}, acc11 = {0.f,0.f,0.f,0.f};
  int sr = tid >> 2, sk = (tid & 3) * 8;
  for (int k0 = 0; k0 < K; k0 += 32) {
    __syncthreads();
    *(uint4*)(&Al[sr * 40 + sk]) = *(const uint4*)(A + (size_t)(m0 + sr) * K + k0 + sk);
    *(uint4*)(&Bl[sr * 40 + sk]) = *(const uint4*)(Bt + (size_t)(n0 + sr) * K + k0 + sk);
    __syncthreads();
    short8 a0 = *(const short8*)(&Al[(rw + l16) * 40 + q * 8]);
    short8 a1 = *(const short8*)(&Al[(rw + 16 + l16) * 40 + q * 8]);
    short8 b0 = *(const short8*)(&Bl[(cw + l16) * 40 + q * 8]);
    short8 b1 = *(const short8*)(&Bl[(cw + 16 + l16) * 40 + q * 8]);
    acc00 = __builtin_amdgcn_mfma_f32_16x16x32_bf16(a0, b0, acc00, 0, 0, 0);
    acc01 = __builtin_amdgcn_mfma_f32_16x16x32_bf16(a0, b1, acc01, 0, 0, 0);
    acc10 = __builtin_amdgcn_mfma_f32_16x16x32_bf16(a1, b0, acc10, 0, 0, 0);
    acc11 = __builtin_amdgcn_mfma_f32_16x16x32_bf16(a1, b1, acc11, 0, 0, 0);
  }
  floatx4 accs[2][2] = {{acc00, acc01}, {acc10, acc11}};
#pragma unroll
  for (int mt = 0; mt < 2; ++mt) {
#pragma unroll
    for (int nt = 0; nt < 2; ++nt) {
      int n = n0 + cw + nt * 16 + l16;
      float bsv = bias[n];
#pragma unroll
      for (int r = 0; r < 4; ++r) {
        int m = m0 + rw + mt * 16 + q * 4 + r;
        float val = accs[mt][nt][r] + bsv;
        if (do_silu) val = val / (1.0f + __expf(-val));
        size_t mrow = row_remap ? (size_t)(2048 + m + ((m >> 11) << 12)) : (size_t)m;
        if (c_fp32) ((float*)C)[mrow * N + n] = val;
        else ((unsigned short*)C)[mrow * N + n] = f2bf(val);
      }
    }
  }
}

// ---------------- chunked IIR scan (phase A) -------------------------------
// Per (dir, b, chunk, c-pair): zero-state local scan of 64 steps.
//   F[t] = sum_j delta[h,j,d] * Vp[b, 2048 + t -/+ l_j, c]   (pads are zero)
//   sg = g*sg + F;  sy = g*sy + sg;  store sy (bf16); record exit state (fp32).
__global__ __launch_bounds__(256) void scan_chunks(const unsigned short* __restrict__ Vp,
                                                   const float* __restrict__ dp,
                                                   const float* __restrict__ dn,
                                                   unsigned short* __restrict__ ypl,
                                                   unsigned short* __restrict__ ynl,
                                                   float* __restrict__ Sy_ex,
                                                   float* __restrict__ SG_ex) {
  int z = blockIdx.z;            // dir*2 + b
  int dir = z >> 1, b = z & 1;
  int chunk = blockIdx.y;
  int c0 = (blockIdx.x * 256 + threadIdx.x) * 2;   // two channels per thread
  int h = c0 >> 7, d = c0 & 127;
  const float* dt = (dir ? dn : dp) + (size_t)(h * NTAP) * HD + d;
  float2 dreg[NTAP];
#pragma unroll
  for (int j = 0; j < NTAP; ++j) dreg[j] = *(const float2*)(dt + j * HD);
  const unsigned short* Vb = Vp + (size_t)b * VPROWS * D1 + c0;
  unsigned short* yl = (dir ? ynl : ypl) + (size_t)b * NSEQ * D1 + c0;
  float sy0 = 0.f, sy1 = 0.f, sg0 = 0.f, sg1 = 0.f;
  if (!dir) {
    int t = chunk * CLEN;
    const unsigned short* Vrow = Vb + (size_t)(2048 + t) * D1;
    for (int i = 0; i < CLEN; ++i) {
      float F0 = 0.f, F1 = 0.f;
#pragma unroll
      for (int j = 0; j < NTAP; ++j) {
        unsigned int pk = *(const unsigned int*)(Vrow - (ptrdiff_t)TAPS[j] * D1);
        F0 += dreg[j].x * bf2f((unsigned short)(pk & 0xffffu));
        F1 += dreg[j].y * bf2f((unsigned short)(pk >> 16));
      }
      sg0 = GAMMA_F * sg0 + F0; sy0 = GAMMA_F * sy0 + sg0;
      sg1 = GAMMA_F * sg1 + F1; sy1 = GAMMA_F * sy1 + sg1;
      unsigned int pack = (unsigned int)f2bf(sy0) | ((unsigned int)f2bf(sy1) << 16);
      *(unsigned int*)(yl + (size_t)(t + i) * D1) = pack;
      Vrow += D1;
    }
  } else {
    int tstart = (NSEQ - 1) - chunk * CLEN;        // reversed time
    const unsigned short* Vrow = Vb + (size_t)(2048 + tstart) * D1;
    for (int i = 0; i < CLEN; ++i) {
      float F0 = 0.f, F1 = 0.f;
#pragma unroll
      for (int j = 0; j < NTAP; ++j) {
        unsigned int pk = *(const unsigned int*)(Vrow + (ptrdiff_t)TAPS[j] * D1);
        F0 += dreg[j].x * bf2f((unsigned short)(pk & 0xffffu));
        F1 += dreg[j].y * bf2f((unsigned short)(pk >> 16));
      }
      sg0 = GAMMA_F * sg0 + F0; sy0 = GAMMA_F * sy0 + sg0;
      sg1 = GAMMA_F * sg1 + F1; sy1 = GAMMA_F * sy1 + sg1;
      unsigned int pack = (unsigned int)f2bf(sy0) | ((unsigned int)f2bf(sy1) << 16);
      *(unsigned int*)(yl + (size_t)(tstart - i) * D1) = pack;
      Vrow -= D1;
    }
  }
  size_t sidx = ((size_t)z * NCHUNK + chunk) * D1 + c0;
  Sy_ex[sidx] = sy0; Sy_ex[sidx + 1] = sy1;
  SG_ex[sidx] = sg0; SG_ex[sidx + 1] = sg1;
}

// ---------------- chunk-state scan (phase B) -------------------------------
// entry(k+1) = local_exit(k) + homogeneous fixup from entry(k), L = 64.
__global__ __launch_bounds__(256) void state_scan(const float* __restrict__ Sy_ex,
                                                  const float* __restrict__ SG_ex,
                                                  float* __restrict__ Sy_in,
                                                  float* __restrict__ SG_in) {
  int idx = blockIdx.x * 256 + threadIdx.x;   // z*2048 + c, total 4*2048
  if (idx >= 4 * D1) return;
  int z = idx >> 11, c = idx & (D1 - 1);
  const float g64 = 0.937975f;                 // 0.999^64
  float ey = 0.f, eg = 0.f;
  for (int k = 0; k < NCHUNK; ++k) {
    size_t s = ((size_t)z * NCHUNK + k) * D1 + c;
    Sy_in[s] = ey; SG_in[s] = eg;
    float lex = Sy_ex[s], lgx = SG_ex[s];
    ey = lex + g64 * (ey + 64.0f * eg);
    eg = lgx + g64 * eg;
  }
}

// ---------------- combine + gate (phase C) ---------------------------------
// y = [y+loc + g^Dp (y_in + Dp G_in)] + [y-loc + g^Dn (...)] + tz*V;  g = U*y
__global__ __launch_bounds__(256) void combine_kernel(const unsigned short* __restrict__ ypl,
                                                      const unsigned short* __restrict__ ynl,
                                                      const unsigned short* __restrict__ Vp,
                                                      const float* __restrict__ Sy_in,
                                                      const float* __restrict__ SG_in,
                                                      const float* __restrict__ tz,
                                                      const unsigned short* __restrict__ U,
                                                      unsigned short* __restrict__ G) {
  int e = blockIdx.x * 256 + threadIdx.x;     // [b][t][c]
  int c = e & (D1 - 1);
  int r = e >> 11;
  int t = r & (NSEQ - 1);
  int b = r >> 11;
  int kp = t >> 6;  float dpD = (float)((t & 63) + 1);
  int tau = (NSEQ - 1) - t;
  int kn = tau >> 6; float dnD = (float)((tau & 63) + 1);
  float gp = __expf(dpD * LN_G);
  float gn = __expf(dnD * LN_G);
  size_t ix = (size_t)r * D1 + c;
  size_t sp = ((size_t)(b) * NCHUNK + kp) * D1 + c;          // z = b (pos)
  size_t sn = ((size_t)(2 + b) * NCHUNK + kn) * D1 + c;      // z = 2+b (neg)
  float accp = bf2f(ypl[ix]) + gp * (Sy_in[sp] + dpD * SG_in[sp]);
  float accn = bf2f(ynl[ix]) + gn * (Sy_in[sn] + dnD * SG_in[sn]);
  float vv = bf2f(Vp[((size_t)b * VPROWS + 2048 + t) * D1 + c]);
  float ytot = accp + accn + tz[c] * vv;
  G[ix] = f2bf(bf2f(U[ix]) * ytot);
}

// ---------------------------------------------------------------------------
extern "C" void kernel_launch(void* const* d_in, const int* in_sizes, int n_in,
                              void* d_out, int out_size, void* d_ws, size_t ws_size,
                              hipStream_t stream) {
  const float* x      = (const float*)d_in[0];
  const float* Wu     = (const float*)d_in[1];
  const float* bu     = (const float*)d_in[2];
  const float* Wv     = (const float*)d_in[3];
  const float* bv     = (const float*)d_in[4];
  const float* Wo     = (const float*)d_in[5];
  const float* bo     = (const float*)d_in[6];
  const float* a_pos  = (const float*)d_in[7];
  const float* b_pos  = (const float*)d_in[8];
  const float* a_neg  = (const float*)d_in[9];
  const float* b_neg  = (const float*)d_in[10];
  const float* t_zero = (const float*)d_in[11];
  float* out = (float*)d_out;

  char* ws = (char*)d_ws;
  unsigned short* x_bf  = (unsigned short*)ws; ws += (size_t)MROWS * DM * 2;        //  8 MB
  unsigned short* u_ws  = (unsigned short*)ws; ws += (size_t)MROWS * D1 * 2;        // 16 MB (g in-place)
  unsigned short* Vp    = (unsigned short*)ws; ws += (size_t)BB * VPROWS * D1 * 2;  // 48 MB padded V
  unsigned short* ypl   = (unsigned short*)ws; ws += (size_t)MROWS * D1 * 2;        // 16 MB
  unsigned short* ynl   = (unsigned short*)ws; ws += (size_t)MROWS * D1 * 2;        // 16 MB
  unsigned short* WT    = (unsigned short*)ws; ws += (size_t)D1 * DM * 2;           //  4 MB (shared)
  float* kip   = (float*)ws; ws += (size_t)H * NKI * HD * 4;                        // 128 KB
  float* kin   = (float*)ws; ws += (size_t)H * NKI * HD * 4;
  float* dtp   = (float*)ws; ws += (size_t)H * NTAP * HD * 4;                       // 229 KB
  float* dtn   = (float*)ws; ws += (size_t)H * NTAP * HD * 4;
  float* Sy_ex = (float*)ws; ws += (size_t)4 * NCHUNK * D1 * 4;                     // 1 MB each
  float* SG_ex = (float*)ws; ws += (size_t)4 * NCHUNK * D1 * 4;
  float* Sy_in = (float*)ws; ws += (size_t)4 * NCHUNK * D1 * 4;
  float* SG_in = (float*)ws; ws += (size_t)4 * NCHUNK * D1 * 4;

  dim3 tb256(256);
  dim3 tptb(32, 8);
  // zero the V pads (rows [0,2048) and [4096,6144) per b)
  (void)hipMemsetAsync(Vp, 0, (size_t)2048 * D1 * 2, stream);
  (void)hipMemsetAsync(Vp + (size_t)4096 * D1, 0, (size_t)2048 * D1 * 2, stream);
  (void)hipMemsetAsync(Vp + (size_t)VPROWS * D1, 0, (size_t)2048 * D1 * 2, stream);
  (void)hipMemsetAsync(Vp + ((size_t)VPROWS + 4096) * D1, 0, (size_t)2048 * D1 * 2, stream);
  // x -> bf16
  cvt_kernel<<<dim3((MROWS * DM / 4 + 255) / 256), tb256, 0, stream>>>(x, x_bf, MROWS * DM / 4);
  // low-rank kernel factors -> sparse delta tables
  kind_kernel<<<dim3(H), tb256, 0, stream>>>(a_pos, b_pos, kip);
  kind_kernel<<<dim3(H), tb256, 0, stream>>>(a_neg, b_neg, kin);
  dtab_kernel<<<dim3(H), tb256, 0, stream>>>(kip, dtp);
  dtab_kernel<<<dim3(H), tb256, 0, stream>>>(kin, dtn);
  // u = silu(x@Wu+bu); v = silu(x@Wv+bv) into padded layout (WT buffer shared)
  tpc_kernel<<<dim3(D1 / 32, DM / 32), tptb, 0, stream>>>(Wu, WT, DM, D1);
  gemm_bf16<<<dim3(D1 / 64, MROWS / 64), tb256, 0, stream>>>(x_bf, WT, bu, u_ws, MROWS, D1, DM, 1, 0, 0);
  tpc_kernel<<<dim3(D1 / 32, DM / 32), tptb, 0, stream>>>(Wv, WT, DM, D1);
  gemm_bf16<<<dim3(D1 / 64, MROWS / 64), tb256, 0, stream>>>(x_bf, WT, bv, Vp, MROWS, D1, DM, 1, 0, 1);
  // IIR conv: chunked scans -> state scan -> combine+gate (in-place over u)
  scan_chunks<<<dim3(D1 / 512, NCHUNK, 4), tb256, 0, stream>>>(Vp, dtp, dtn, ypl, ynl, Sy_ex, SG_ex);
  state_scan<<<dim3((4 * D1 + 255) / 256), tb256, 0, stream>>>(Sy_ex, SG_ex, Sy_in, SG_in);
  combine_kernel<<<dim3((size_t)MROWS * D1 / 256), tb256, 0, stream>>>(ypl, ynl, Vp, Sy_in, SG_in, t_zero, u_ws, u_ws);
  // out = g @ Wo + bo (fp32)
  tpc_kernel<<<dim3(DM / 32, D1 / 32), tptb, 0, stream>>>(Wo, WT, D1, DM);
  gemm_bf16<<<dim3(DM / 64, MROWS / 64), tb256, 0, stream>>>(u_ws, WT, bo, out, MROWS, DM, D1, 0, 1, 0);
}

// Round 6
// 380.732 us; speedup vs baseline: 1.8130x; 1.0097x over previous
//
#include <hip/hip_runtime.h>
#include <hip/hip_bf16.h>
#include <stdint.h>
#include <stddef.h>

// Problem constants (fixed by the reference)
#define BB 2
#define NSEQ 2048
#define DM 1024
#define H 16
#define HD 128
#define D1 2048
#define NKI 16
#define RANKI 32
#define MROWS (BB * NSEQ)   // 4096 rows for all GEMMs
#define VPROWS 6144         // 2048 zero-pad | 2048 data | 2048 zero-pad
#define NTAP 28
#define NCHUNK 64
#define CLEN 32
#define GAMMA_F 0.999f
#define G_CL 0.9684910f     // 0.999^32 (chunk-length homogeneous decay)
// ln(0.999), for gamma^x = exp(x*ln_g)  (__exp2f collides with glibc; __expf is safe)
#define LN_G (-1.00050033e-3f)

// Sparse-tap positions of delta = (1 - g z)^2 * K  (K piecewise-linear * g^l,
// knots at l = 1 + 136.4j; integer knots j=5 (683), j=10 (1365) give 1 tap).
__device__ constexpr int TAPS[NTAP] = {
  1, 2, 138, 139, 274, 275, 411, 412, 547, 548, 684,
  820, 821, 956, 957, 1093, 1094, 1229, 1230, 1366,
  1502, 1503, 1638, 1639, 1775, 1776, 1911, 1912};

typedef short short8 __attribute__((ext_vector_type(8)));
typedef float floatx4 __attribute__((ext_vector_type(4)));

__device__ __forceinline__ float bf2f(unsigned short u) {
  union { unsigned int i; float f; } v; v.i = ((unsigned int)u) << 16; return v.f;
}
__device__ __forceinline__ unsigned short f2bf(float f) {
  union { float f; unsigned int i; } v; v.f = f;
  unsigned int r = (v.i + 0x7FFFu + ((v.i >> 16) & 1u)) >> 16;
  return (unsigned short)r;
}
// async 16B global->LDS DMA: lane i lands at (wave-uniform) l + i*16 bytes
__device__ __forceinline__ void async16(const unsigned short* g, unsigned short* l) {
  __builtin_amdgcn_global_load_lds(
      (const __attribute__((address_space(1))) unsigned int*)g,
      (__attribute__((address_space(3))) unsigned int*)l, 16, 0, 0);
}

// ---------------- fp32 -> bf16 elementwise convert (vectorized) ------------
__global__ __launch_bounds__(256) void cvt_kernel(const float* __restrict__ in,
                                                  unsigned short* __restrict__ out,
                                                  int n4) {
  int i = blockIdx.x * 256 + threadIdx.x;
  if (i >= n4) return;
  float4 f = ((const float4*)in)[i];
  ushort4 o;
  o.x = f2bf(f.x); o.y = f2bf(f.y); o.z = f2bf(f.z); o.w = f2bf(f.w);
  ((ushort4*)out)[i] = o;
}

// ------- fused transpose+convert: out_bf16[c][r] = in_f32[r][c] ------------
__global__ __launch_bounds__(256) void tpc_kernel(const float* __restrict__ in,
                                                  unsigned short* __restrict__ out,
                                                  int rows, int cols) {
  __shared__ unsigned short t[32][33];
  int bx = blockIdx.x * 32, by = blockIdx.y * 32;
  int tx = threadIdx.x, ty = threadIdx.y; // blockDim = (32,8)
#pragma unroll
  for (int j = 0; j < 32; j += 8)
    t[ty + j][tx] = f2bf(in[(size_t)(by + ty + j) * cols + bx + tx]);
  __syncthreads();
#pragma unroll
  for (int j = 0; j < 32; j += 8)
    out[(size_t)(bx + ty + j) * rows + by + tx] = t[tx][ty + j];
}

// ---------------- k_ind = a @ b per head:  [H][NK][HD] fp32 ----------------
__global__ __launch_bounds__(256) void kind_kernel(const float* __restrict__ a,
                                                   const float* __restrict__ b,
                                                   float* __restrict__ kout) {
  int h = blockIdx.x;
  for (int e = threadIdx.x; e < NKI * HD; e += 256) {
    int k = e >> 7, d = e & 127;
    float s = 0.0f;
#pragma unroll
    for (int r = 0; r < RANKI; ++r)
      s += a[(h * NKI + k) * RANKI + r] * b[(h * RANKI + r) * HD + d];
    kout[(h * NKI + k) * HD + d] = s;
  }
}

// ---- K(l) = interp(kind, l) * gamma^l  (same formula as the direct ref) ---
__device__ __forceinline__ float Kinterp(const float* __restrict__ kk, int l, int d) {
  if (l < 1) return 0.0f;   // l > 2047 never queried (max tap 1912)
  float p = (float)(l - 1) * (15.0f / 2046.0f);
  int lo = (int)p; if (lo > 15) lo = 15;
  int hi = lo + 1; if (hi > 15) hi = 15;
  float w = p - (float)lo;
  float v = kk[lo * HD + d] * (1.0f - w) + kk[hi * HD + d] * w;
  return v * __powf(GAMMA_F, (float)l);
}

// ---------------- delta table: dtab[h][j][d] = (1-gz)^2 K at tap l_j -------
__global__ __launch_bounds__(256) void dtab_kernel(const float* __restrict__ kind,
                                                   float* __restrict__ dtab) {
  int h = blockIdx.x;
  const float* kk = kind + h * NKI * HD;
  for (int e = threadIdx.x; e < NTAP * HD; e += 256) {
    int j = e >> 7, d = e & 127;
    int l = TAPS[j];
    float K0 = Kinterp(kk, l, d);
    float K1 = Kinterp(kk, l - 1, d);
    float K2 = Kinterp(kk, l - 2, d);
    dtab[(h * NTAP + j) * HD + d] = K0 - 2.0f * GAMMA_F * K1 + (GAMMA_F * GAMMA_F) * K2;
  }
}

// ---------------- bf16 MFMA GEMM: C = [silu](A @ Bt^T + bias) --------------
// m97 structure: 128x128 tile, BK=32, global_load_lds width=16 staging
// (LDS unpadded & lane-ordered -- required by the DMA), 4 waves each 64x64.
__global__ __launch_bounds__(256) void gemm_bf16(const unsigned short* __restrict__ A,
                                                 const unsigned short* __restrict__ Bt,
                                                 const float* __restrict__ bias,
                                                 void* __restrict__ C,
                                                 int M, int N, int K,
                                                 int do_silu, int c_fp32, int row_remap) {
  __shared__ unsigned short Al[128 * 32];   // 8 KB
  __shared__ unsigned short Bl[128 * 32];   // 8 KB
  int m0 = blockIdx.y * 128, n0 = blockIdx.x * 128;
  int tid = threadIdx.x;
  int lane = tid & 63, w = tid >> 6;
  int rw = (w >> 1) * 64, cw = (w & 1) * 64;
  int q = lane >> 4, l16 = lane & 15;
  floatx4 acc[4][4];
#pragma unroll
  for (int mt = 0; mt < 4; ++mt)
#pragma unroll
    for (int nt = 0; nt < 4; ++nt) acc[mt][nt] = (floatx4){0.f, 0.f, 0.f, 0.f};
  int grow = tid >> 2;            // row 0..63 within a 64-row segment
  int gcol = (tid & 3) * 8;       // k-offset (elems)
  const unsigned short* A0 = A + (size_t)(m0 + grow) * K + gcol;
  const unsigned short* A1 = A0 + (size_t)64 * K;
  const unsigned short* B0 = Bt + (size_t)(n0 + grow) * K + gcol;
  const unsigned short* B1 = B0 + (size_t)64 * K;
  unsigned short* AlW0 = &Al[w * 512];        // wave-uniform LDS bases
  unsigned short* AlW1 = &Al[2048 + w * 512];
  unsigned short* BlW0 = &Bl[w * 512];
  unsigned short* BlW1 = &Bl[2048 + w * 512];
  for (int k0 = 0; k0 < K; k0 += 32) {
    __syncthreads();
    async16(A0 + k0, AlW0);
    async16(A1 + k0, AlW1);
    async16(B0 + k0, BlW0);
    async16(B1 + k0, BlW1);
    __syncthreads();   // drains vmcnt -> staged data visible
    short8 af[4], bfr[4];
#pragma unroll
    for (int i = 0; i < 4; ++i) {
      af[i]  = *(const short8*)(&Al[(rw + i * 16 + l16) * 32 + q * 8]);
      bfr[i] = *(const short8*)(&Bl[(cw + i * 16 + l16) * 32 + q * 8]);
    }
#pragma unroll
    for (int mt = 0; mt < 4; ++mt)
#pragma unroll
      for (int nt = 0; nt < 4; ++nt)
        acc[mt][nt] = __builtin_amdgcn_mfma_f32_16x16x32_bf16(af[mt], bfr[nt], acc[mt][nt], 0, 0, 0);
  }
  // epilogue: D[row = q*4 + r][col = lane&15] per 16x16 tile (verified mapping)
#pragma unroll
  for (int mt = 0; mt < 4; ++mt) {
#pragma unroll
    for (int nt = 0; nt < 4; ++nt) {
      int n = n0 + cw + nt * 16 + l16;
      float bsv = bias[n];
#pragma unroll
      for (int r = 0; r < 4; ++r) {
        int m = m0 + rw + mt * 16 + q * 4 + r;
        float val = acc[mt][nt][r] + bsv;
        if (do_silu) val = val / (1.0f + __expf(-val));
        size_t mrow = row_remap ? (size_t)(2048 + m + ((m >> 11) << 12)) : (size_t)m;
        if (c_fp32) ((float*)C)[mrow * N + n] = val;
        else ((unsigned short*)C)[mrow * N + n] = f2bf(val);
      }
    }
  }
}

// ---------------- chunked IIR scan (phase A) -------------------------------
// Per (dir, b, chunk, c-pair): zero-state local scan of CLEN steps.
//   F[t] = sum_j delta[h,j,d] * Vp[b, 2048 + t -/+ l_j, c]   (pads are zero)
//   sg = g*sg + F;  sy = g*sy + sg;  store sy (bf16); record exit state (fp32).
__global__ __launch_bounds__(256) void scan_chunks(const unsigned short* __restrict__ Vp,
                                                   const float* __restrict__ dp,
                                                   const float* __restrict__ dn,
                                                   unsigned short* __restrict__ ypl,
                                                   unsigned short* __restrict__ ynl,
                                                   float* __restrict__ Sy_ex,
                                                   float* __restrict__ SG_ex) {
  int z = blockIdx.z;            // dir*2 + b
  int dir = z >> 1, b = z & 1;
  int chunk = blockIdx.y;
  int c0 = (blockIdx.x * 256 + threadIdx.x) * 2;   // two channels per thread
  int h = c0 >> 7, d = c0 & 127;
  const float* dt = (dir ? dn : dp) + (size_t)(h * NTAP) * HD + d;
  float2 dreg[NTAP];
#pragma unroll
  for (int j = 0; j < NTAP; ++j) dreg[j] = *(const float2*)(dt + j * HD);
  const unsigned short* Vb = Vp + (size_t)b * VPROWS * D1 + c0;
  unsigned short* yl = (dir ? ynl : ypl) + (size_t)b * NSEQ * D1 + c0;
  float sy0 = 0.f, sy1 = 0.f, sg0 = 0.f, sg1 = 0.f;
  if (!dir) {
    int t = chunk * CLEN;
    const unsigned short* Vrow = Vb + (size_t)(2048 + t) * D1;
    for (int i = 0; i < CLEN; ++i) {
      float F0 = 0.f, F1 = 0.f;
#pragma unroll
      for (int j = 0; j < NTAP; ++j) {
        unsigned int pk = *(const unsigned int*)(Vrow - (ptrdiff_t)TAPS[j] * D1);
        F0 += dreg[j].x * bf2f((unsigned short)(pk & 0xffffu));
        F1 += dreg[j].y * bf2f((unsigned short)(pk >> 16));
      }
      sg0 = GAMMA_F * sg0 + F0; sy0 = GAMMA_F * sy0 + sg0;
      sg1 = GAMMA_F * sg1 + F1; sy1 = GAMMA_F * sy1 + sg1;
      unsigned int pack = (unsigned int)f2bf(sy0) | ((unsigned int)f2bf(sy1) << 16);
      *(unsigned int*)(yl + (size_t)(t + i) * D1) = pack;
      Vrow += D1;
    }
  } else {
    int tstart = (NSEQ - 1) - chunk * CLEN;        // reversed time
    const unsigned short* Vrow = Vb + (size_t)(2048 + tstart) * D1;
    for (int i = 0; i < CLEN; ++i) {
      float F0 = 0.f, F1 = 0.f;
#pragma unroll
      for (int j = 0; j < NTAP; ++j) {
        unsigned int pk = *(const unsigned int*)(Vrow + (ptrdiff_t)TAPS[j] * D1);
        F0 += dreg[j].x * bf2f((unsigned short)(pk & 0xffffu));
        F1 += dreg[j].y * bf2f((unsigned short)(pk >> 16));
      }
      sg0 = GAMMA_F * sg0 + F0; sy0 = GAMMA_F * sy0 + sg0;
      sg1 = GAMMA_F * sg1 + F1; sy1 = GAMMA_F * sy1 + sg1;
      unsigned int pack = (unsigned int)f2bf(sy0) | ((unsigned int)f2bf(sy1) << 16);
      *(unsigned int*)(yl + (size_t)(tstart - i) * D1) = pack;
      Vrow -= D1;
    }
  }
  size_t sidx = ((size_t)z * NCHUNK + chunk) * D1 + c0;
  Sy_ex[sidx] = sy0; Sy_ex[sidx + 1] = sy1;
  SG_ex[sidx] = sg0; SG_ex[sidx + 1] = sg1;
}

// ---------------- chunk-state scan (phase B) -------------------------------
// entry(k+1) = local_exit(k) + homogeneous fixup from entry(k), L = CLEN.
__global__ __launch_bounds__(256) void state_scan(const float* __restrict__ Sy_ex,
                                                  const float* __restrict__ SG_ex,
                                                  float* __restrict__ Sy_in,
                                                  float* __restrict__ SG_in) {
  int idx = blockIdx.x * 256 + threadIdx.x;   // z*2048 + c, total 4*2048
  if (idx >= 4 * D1) return;
  int z = idx >> 11, c = idx & (D1 - 1);
  float ey = 0.f, eg = 0.f;
  for (int k = 0; k < NCHUNK; ++k) {
    size_t s = ((size_t)z * NCHUNK + k) * D1 + c;
    Sy_in[s] = ey; SG_in[s] = eg;
    float lex = Sy_ex[s], lgx = SG_ex[s];
    ey = lex + G_CL * (ey + (float)CLEN * eg);
    eg = lgx + G_CL * eg;
  }
}

// ---------------- combine + gate (phase C) ---------------------------------
// y = [y+loc + g^Dp (y_in + Dp G_in)] + [y-loc + g^Dn (...)] + tz*V;  g = U*y
__global__ __launch_bounds__(256) void combine_kernel(const unsigned short* __restrict__ ypl,
                                                      const unsigned short* __restrict__ ynl,
                                                      const unsigned short* __restrict__ Vp,
                                                      const float* __restrict__ Sy_in,
                                                      const float* __restrict__ SG_in,
                                                      const float* __restrict__ tz,
                                                      const unsigned short* __restrict__ U,
                                                      unsigned short* __restrict__ G) {
  int e = blockIdx.x * 256 + threadIdx.x;     // [b][t][c]
  int c = e & (D1 - 1);
  int r = e >> 11;
  int t = r & (NSEQ - 1);
  int b = r >> 11;
  int kp = t >> 5;  float dpD = (float)((t & 31) + 1);
  int tau = (NSEQ - 1) - t;
  int kn = tau >> 5; float dnD = (float)((tau & 31) + 1);
  float gp = __expf(dpD * LN_G);
  float gn = __expf(dnD * LN_G);
  size_t ix = (size_t)r * D1 + c;
  size_t sp = ((size_t)(b) * NCHUNK + kp) * D1 + c;          // z = b (pos)
  size_t sn = ((size_t)(2 + b) * NCHUNK + kn) * D1 + c;      // z = 2+b (neg)
  float accp = bf2f(ypl[ix]) + gp * (Sy_in[sp] + dpD * SG_in[sp]);
  float accn = bf2f(ynl[ix]) + gn * (Sy_in[sn] + dnD * SG_in[sn]);
  float vv = bf2f(Vp[((size_t)b * VPROWS + 2048 + t) * D1 + c]);
  float ytot = accp + accn + tz[c] * vv;
  G[ix] = f2bf(bf2f(U[ix]) * ytot);
}

// ---------------------------------------------------------------------------
extern "C" void kernel_launch(void* const* d_in, const int* in_sizes, int n_in,
                              void* d_out, int out_size, void* d_ws, size_t ws_size,
                              hipStream_t stream) {
  const float* x      = (const float*)d_in[0];
  const float* Wu     = (const float*)d_in[1];
  const float* bu     = (const float*)d_in[2];
  const float* Wv     = (const float*)d_in[3];
  const float* bv     = (const float*)d_in[4];
  const float* Wo     = (const float*)d_in[5];
  const float* bo     = (const float*)d_in[6];
  const float* a_pos  = (const float*)d_in[7];
  const float* b_pos  = (const float*)d_in[8];
  const float* a_neg  = (const float*)d_in[9];
  const float* b_neg  = (const float*)d_in[10];
  const float* t_zero = (const float*)d_in[11];
  float* out = (float*)d_out;

  char* ws = (char*)d_ws;
  unsigned short* x_bf  = (unsigned short*)ws; ws += (size_t)MROWS * DM * 2;        //  8 MB
  unsigned short* u_ws  = (unsigned short*)ws; ws += (size_t)MROWS * D1 * 2;        // 16 MB (g in-place)
  unsigned short* Vp    = (unsigned short*)ws; ws += (size_t)BB * VPROWS * D1 * 2;  // 48 MB padded V
  unsigned short* ypl   = (unsigned short*)ws; ws += (size_t)MROWS * D1 * 2;        // 16 MB
  unsigned short* ynl   = (unsigned short*)ws; ws += (size_t)MROWS * D1 * 2;        // 16 MB
  unsigned short* WT    = (unsigned short*)ws; ws += (size_t)D1 * DM * 2;           //  4 MB (shared)
  float* kip   = (float*)ws; ws += (size_t)H * NKI * HD * 4;                        // 128 KB
  float* kin   = (float*)ws; ws += (size_t)H * NKI * HD * 4;
  float* dtp   = (float*)ws; ws += (size_t)H * NTAP * HD * 4;                       // 229 KB
  float* dtn   = (float*)ws; ws += (size_t)H * NTAP * HD * 4;
  float* Sy_ex = (float*)ws; ws += (size_t)4 * NCHUNK * D1 * 4;                     // 2 MB each
  float* SG_ex = (float*)ws; ws += (size_t)4 * NCHUNK * D1 * 4;
  float* Sy_in = (float*)ws; ws += (size_t)4 * NCHUNK * D1 * 4;
  float* SG_in = (float*)ws; ws += (size_t)4 * NCHUNK * D1 * 4;

  dim3 tb256(256);
  dim3 tptb(32, 8);
  // zero the V pads (rows [0,2048) and [4096,6144) per b)
  (void)hipMemsetAsync(Vp, 0, (size_t)2048 * D1 * 2, stream);
  (void)hipMemsetAsync(Vp + (size_t)4096 * D1, 0, (size_t)2048 * D1 * 2, stream);
  (void)hipMemsetAsync(Vp + (size_t)VPROWS * D1, 0, (size_t)2048 * D1 * 2, stream);
  (void)hipMemsetAsync(Vp + ((size_t)VPROWS + 4096) * D1, 0, (size_t)2048 * D1 * 2, stream);
  // x -> bf16
  cvt_kernel<<<dim3((MROWS * DM / 4 + 255) / 256), tb256, 0, stream>>>(x, x_bf, MROWS * DM / 4);
  // low-rank kernel factors -> sparse delta tables
  kind_kernel<<<dim3(H), tb256, 0, stream>>>(a_pos, b_pos, kip);
  kind_kernel<<<dim3(H), tb256, 0, stream>>>(a_neg, b_neg, kin);
  dtab_kernel<<<dim3(H), tb256, 0, stream>>>(kip, dtp);
  dtab_kernel<<<dim3(H), tb256, 0, stream>>>(kin, dtn);
  // u = silu(x@Wu+bu); v = silu(x@Wv+bv) into padded layout (WT buffer shared)
  tpc_kernel<<<dim3(D1 / 32, DM / 32), tptb, 0, stream>>>(Wu, WT, DM, D1);
  gemm_bf16<<<dim3(D1 / 128, MROWS / 128), tb256, 0, stream>>>(x_bf, WT, bu, u_ws, MROWS, D1, DM, 1, 0, 0);
  tpc_kernel<<<dim3(D1 / 32, DM / 32), tptb, 0, stream>>>(Wv, WT, DM, D1);
  gemm_bf16<<<dim3(D1 / 128, MROWS / 128), tb256, 0, stream>>>(x_bf, WT, bv, Vp, MROWS, D1, DM, 1, 0, 1);
  // IIR conv: chunked scans -> state scan -> combine+gate (in-place over u)
  scan_chunks<<<dim3(D1 / 512, NCHUNK, 4), tb256, 0, stream>>>(Vp, dtp, dtn, ypl, ynl, Sy_ex, SG_ex);
  state_scan<<<dim3((4 * D1 + 255) / 256), tb256, 0, stream>>>(Sy_ex, SG_ex, Sy_in, SG_in);
  combine_kernel<<<dim3((size_t)MROWS * D1 / 256), tb256, 0, stream>>>(ypl, ynl, Vp, Sy_in, SG_in, t_zero, u_ws, u_ws);
  // out = g @ Wo + bo (fp32)
  tpc_kernel<<<dim3(DM / 32, D1 / 32), tptb, 0, stream>>>(Wo, WT, D1, DM);
  gemm_bf16<<<dim3(DM / 128, MROWS / 128), tb256, 0, stream>>>(u_ws, WT, bo, out, MROWS, DM, D1, 0, 1, 0);
}

// Round 7
// 346.322 us; speedup vs baseline: 1.9931x; 1.0994x over previous
//
#include <hip/hip_runtime.h>
#include <hip/hip_bf16.h>
#include <stdint.h>
#include <stddef.h>

// Problem constants (fixed by the reference)
#define BB 2
#define NSEQ 2048
#define DM 1024
#define H 16
#define HD 128
#define D1 2048
#define NKI 16
#define RANKI 32
#define MROWS (BB * NSEQ)   // 4096 rows for all GEMMs
#define VPROWS 6144         // 2048 zero-pad | 2048 data | 2048 zero-pad
#define NTAP 28
#define NCHUNK 64
#define CLEN 32
#define GAMMA_F 0.999f
#define G_CL 0.9684910f     // 0.999^32 (chunk-length homogeneous decay)
// ln(0.999), for gamma^x = exp(x*ln_g)  (__exp2f collides with glibc; __expf is safe)
#define LN_G (-1.00050033e-3f)

// Sparse-tap positions of delta = (1 - g z)^2 * K  (K piecewise-linear * g^l,
// knots at l = 1 + 136.4j; integer knots j=5 (683), j=10 (1365) give 1 tap).
__device__ constexpr int TAPS[NTAP] = {
  1, 2, 138, 139, 274, 275, 411, 412, 547, 548, 684,
  820, 821, 956, 957, 1093, 1094, 1229, 1230, 1366,
  1502, 1503, 1638, 1639, 1775, 1776, 1911, 1912};

typedef short short8 __attribute__((ext_vector_type(8)));
typedef float floatx4 __attribute__((ext_vector_type(4)));

__device__ __forceinline__ float bf2f(unsigned short u) {
  union { unsigned int i; float f; } v; v.i = ((unsigned int)u) << 16; return v.f;
}
__device__ __forceinline__ unsigned short f2bf(float f) {
  union { float f; unsigned int i; } v; v.f = f;
  unsigned int r = (v.i + 0x7FFFu + ((v.i >> 16) & 1u)) >> 16;
  return (unsigned short)r;
}
// async 16B global->LDS DMA: lane i lands at (wave-uniform) l + i*16 bytes
__device__ __forceinline__ void async16(const unsigned short* g, unsigned short* l) {
  __builtin_amdgcn_global_load_lds(
      (const __attribute__((address_space(1))) unsigned int*)g,
      (__attribute__((address_space(3))) unsigned int*)l, 16, 0, 0);
}

// ---------------- fp32 -> bf16 elementwise convert (vectorized) ------------
__global__ __launch_bounds__(256) void cvt_kernel(const float* __restrict__ in,
                                                  unsigned short* __restrict__ out,
                                                  int n4) {
  int i = blockIdx.x * 256 + threadIdx.x;
  if (i >= n4) return;
  float4 f = ((const float4*)in)[i];
  ushort4 o;
  o.x = f2bf(f.x); o.y = f2bf(f.y); o.z = f2bf(f.z); o.w = f2bf(f.w);
  ((ushort4*)out)[i] = o;
}

// ------- fused transpose+convert: out_bf16[c][r] = in_f32[r][c] ------------
__global__ __launch_bounds__(256) void tpc_kernel(const float* __restrict__ in,
                                                  unsigned short* __restrict__ out,
                                                  int rows, int cols) {
  __shared__ unsigned short t[32][33];
  int bx = blockIdx.x * 32, by = blockIdx.y * 32;
  int tx = threadIdx.x, ty = threadIdx.y; // blockDim = (32,8)
#pragma unroll
  for (int j = 0; j < 32; j += 8)
    t[ty + j][tx] = f2bf(in[(size_t)(by + ty + j) * cols + bx + tx]);
  __syncthreads();
#pragma unroll
  for (int j = 0; j < 32; j += 8)
    out[(size_t)(bx + ty + j) * rows + by + tx] = t[tx][ty + j];
}

// ---- K(l) = interp(kind, l) * gamma^l on an LDS copy of kind --------------
__device__ __forceinline__ float KinterpL(const float* kk, int l, int d) {
  if (l < 1) return 0.0f;   // l > 2047 never queried (max tap 1912)
  float p = (float)(l - 1) * (15.0f / 2046.0f);
  int lo = (int)p; if (lo > 15) lo = 15;
  int hi = lo + 1; if (hi > 15) hi = 15;
  float w = p - (float)lo;
  float v = kk[lo * HD + d] * (1.0f - w) + kk[hi * HD + d] * w;
  return v * __powf(GAMMA_F, (float)l);
}

// ---- fused: kind = a@b per (head,dir) -> delta table (1-gz)^2 K at taps ---
__global__ __launch_bounds__(256) void kdtab_kernel(const float* __restrict__ ap,
                                                    const float* __restrict__ bp,
                                                    const float* __restrict__ an,
                                                    const float* __restrict__ bn,
                                                    float* __restrict__ dtp,
                                                    float* __restrict__ dtn) {
  __shared__ float kk[NKI * HD];  // 8 KB
  int h = blockIdx.x, dir = blockIdx.y;
  const float* a = (dir ? an : ap) + h * NKI * RANKI;
  const float* b = (dir ? bn : bp) + h * RANKI * HD;
  for (int e = threadIdx.x; e < NKI * HD; e += 256) {
    int k = e >> 7, d = e & 127;
    float s = 0.0f;
#pragma unroll
    for (int r = 0; r < RANKI; ++r) s += a[k * RANKI + r] * b[r * HD + d];
    kk[e] = s;
  }
  __syncthreads();
  float* dt = (dir ? dtn : dtp) + (size_t)h * NTAP * HD;
  for (int e = threadIdx.x; e < NTAP * HD; e += 256) {
    int j = e >> 7, d = e & 127;
    int l = TAPS[j];
    float K0 = KinterpL(kk, l, d);
    float K1 = KinterpL(kk, l - 1, d);
    float K2 = KinterpL(kk, l - 2, d);
    dt[e] = K0 - 2.0f * GAMMA_F * K1 + (GAMMA_F * GAMMA_F) * K2;
  }
}

// ---------------- bf16 MFMA GEMM, double-buffered LDS ----------------------
// C = [silu](A @ Bt^T + bias). 128x128 tile, BK=32, global_load_lds width=16.
// uv_mode: N=4096 fused u|v; n<2048 -> C (u), n>=2048 -> C2 (Vp, row-remapped).
__global__ __launch_bounds__(256) void gemm_bf16(const unsigned short* __restrict__ A,
                                                 const unsigned short* __restrict__ Bt,
                                                 const float* __restrict__ bias,
                                                 const float* __restrict__ bias2,
                                                 void* __restrict__ C,
                                                 void* __restrict__ C2,
                                                 int M, int N, int K,
                                                 int do_silu, int c_fp32, int uv_mode) {
  __shared__ unsigned short Al[2][128 * 32];   // 2 x 8 KB
  __shared__ unsigned short Bl[2][128 * 32];   // 2 x 8 KB
  int m0 = blockIdx.y * 128, n0 = blockIdx.x * 128;
  int tid = threadIdx.x;
  int lane = tid & 63, w = tid >> 6;
  int rw = (w >> 1) * 64, cw = (w & 1) * 64;
  int q = lane >> 4, l16 = lane & 15;
  floatx4 acc[4][4];
#pragma unroll
  for (int mt = 0; mt < 4; ++mt)
#pragma unroll
    for (int nt = 0; nt < 4; ++nt) acc[mt][nt] = (floatx4){0.f, 0.f, 0.f, 0.f};
  int grow = tid >> 2;            // row 0..63 within a 64-row segment
  int gcol = (tid & 3) * 8;       // k-offset (elems)
  const unsigned short* A0 = A + (size_t)(m0 + grow) * K + gcol;
  const unsigned short* A1 = A0 + (size_t)64 * K;
  const unsigned short* B0 = Bt + (size_t)(n0 + grow) * K + gcol;
  const unsigned short* B1 = B0 + (size_t)64 * K;
  int woff = w * 512;             // wave-uniform LDS element base
  int nIter = K >> 5;
  // prologue: stage iter 0 into buffer 0
  async16(A0, &Al[0][woff]);
  async16(A1, &Al[0][2048 + woff]);
  async16(B0, &Bl[0][woff]);
  async16(B1, &Bl[0][2048 + woff]);
  int p = 0;
  for (int i = 0; i < nIter; ++i) {
    __syncthreads();   // drains vmcnt: buffer p staged; prev reads of p^1 done
    if (i + 1 < nIter) {           // prefetch i+1 into p^1, overlaps MFMA below
      int kn = (i + 1) << 5;
      async16(A0 + kn, &Al[p ^ 1][woff]);
      async16(A1 + kn, &Al[p ^ 1][2048 + woff]);
      async16(B0 + kn, &Bl[p ^ 1][woff]);
      async16(B1 + kn, &Bl[p ^ 1][2048 + woff]);
    }
    short8 af[4], bfr[4];
#pragma unroll
    for (int i4 = 0; i4 < 4; ++i4) {
      af[i4]  = *(const short8*)(&Al[p][(rw + i4 * 16 + l16) * 32 + q * 8]);
      bfr[i4] = *(const short8*)(&Bl[p][(cw + i4 * 16 + l16) * 32 + q * 8]);
    }
#pragma unroll
    for (int mt = 0; mt < 4; ++mt)
#pragma unroll
      for (int nt = 0; nt < 4; ++nt)
        acc[mt][nt] = __builtin_amdgcn_mfma_f32_16x16x32_bf16(af[mt], bfr[nt], acc[mt][nt], 0, 0, 0);
    p ^= 1;
  }
  // epilogue: D[row = q*4 + r][col = lane&15] per 16x16 tile (verified mapping)
  int isv = uv_mode && (n0 >= 2048);
  int ldc = uv_mode ? 2048 : N;
  int ncb = isv ? (n0 - 2048) : n0;
  const float* buse = isv ? bias2 : bias;
#pragma unroll
  for (int mt = 0; mt < 4; ++mt) {
#pragma unroll
    for (int nt = 0; nt < 4; ++nt) {
      int n = ncb + cw + nt * 16 + l16;
      float bsv = buse[n];
#pragma unroll
      for (int r = 0; r < 4; ++r) {
        int m = m0 + rw + mt * 16 + q * 4 + r;
        float val = acc[mt][nt][r] + bsv;
        if (do_silu) val = val / (1.0f + __expf(-val));
        if (isv) {
          size_t mrow = (size_t)(2048 + m + ((m >> 11) << 12));  // padded-V row
          ((unsigned short*)C2)[mrow * 2048 + n] = f2bf(val);
        } else if (c_fp32) {
          ((float*)C)[(size_t)m * ldc + n] = val;
        } else {
          ((unsigned short*)C)[(size_t)m * ldc + n] = f2bf(val);
        }
      }
    }
  }
}

// ---------------- chunked IIR scan (phase A) -------------------------------
// Per (dir, b, chunk, c-pair): zero-state local scan of CLEN steps.
//   F[t] = sum_j delta[h,j,d] * Vp[b, 2048 + t -/+ l_j, c]   (pads are zero)
//   sg = g*sg + F;  sy = g*sy + sg;  store sy (bf16); record exit state (fp32).
__global__ __launch_bounds__(256) void scan_chunks(const unsigned short* __restrict__ Vp,
                                                   const float* __restrict__ dp,
                                                   const float* __restrict__ dn,
                                                   unsigned short* __restrict__ ypl,
                                                   unsigned short* __restrict__ ynl,
                                                   float* __restrict__ Sy_ex,
                                                   float* __restrict__ SG_ex) {
  int z = blockIdx.z;            // dir*2 + b
  int dir = z >> 1, b = z & 1;
  int chunk = blockIdx.y;
  int c0 = (blockIdx.x * 256 + threadIdx.x) * 2;   // two channels per thread
  int h = c0 >> 7, d = c0 & 127;
  const float* dt = (dir ? dn : dp) + (size_t)(h * NTAP) * HD + d;
  float2 dreg[NTAP];
#pragma unroll
  for (int j = 0; j < NTAP; ++j) dreg[j] = *(const float2*)(dt + j * HD);
  const unsigned short* Vb = Vp + (size_t)b * VPROWS * D1 + c0;
  unsigned short* yl = (dir ? ynl : ypl) + (size_t)b * NSEQ * D1 + c0;
  float sy0 = 0.f, sy1 = 0.f, sg0 = 0.f, sg1 = 0.f;
  if (!dir) {
    int t = chunk * CLEN;
    const unsigned short* Vrow = Vb + (size_t)(2048 + t) * D1;
    for (int i = 0; i < CLEN; ++i) {
      float F0 = 0.f, F1 = 0.f;
#pragma unroll
      for (int j = 0; j < NTAP; ++j) {
        unsigned int pk = *(const unsigned int*)(Vrow - (ptrdiff_t)TAPS[j] * D1);
        F0 += dreg[j].x * bf2f((unsigned short)(pk & 0xffffu));
        F1 += dreg[j].y * bf2f((unsigned short)(pk >> 16));
      }
      sg0 = GAMMA_F * sg0 + F0; sy0 = GAMMA_F * sy0 + sg0;
      sg1 = GAMMA_F * sg1 + F1; sy1 = GAMMA_F * sy1 + sg1;
      unsigned int pack = (unsigned int)f2bf(sy0) | ((unsigned int)f2bf(sy1) << 16);
      *(unsigned int*)(yl + (size_t)(t + i) * D1) = pack;
      Vrow += D1;
    }
  } else {
    int tstart = (NSEQ - 1) - chunk * CLEN;        // reversed time
    const unsigned short* Vrow = Vb + (size_t)(2048 + tstart) * D1;
    for (int i = 0; i < CLEN; ++i) {
      float F0 = 0.f, F1 = 0.f;
#pragma unroll
      for (int j = 0; j < NTAP; ++j) {
        unsigned int pk = *(const unsigned int*)(Vrow + (ptrdiff_t)TAPS[j] * D1);
        F0 += dreg[j].x * bf2f((unsigned short)(pk & 0xffffu));
        F1 += dreg[j].y * bf2f((unsigned short)(pk >> 16));
      }
      sg0 = GAMMA_F * sg0 + F0; sy0 = GAMMA_F * sy0 + sg0;
      sg1 = GAMMA_F * sg1 + F1; sy1 = GAMMA_F * sy1 + sg1;
      unsigned int pack = (unsigned int)f2bf(sy0) | ((unsigned int)f2bf(sy1) << 16);
      *(unsigned int*)(yl + (size_t)(tstart - i) * D1) = pack;
      Vrow -= D1;
    }
  }
  size_t sidx = ((size_t)z * NCHUNK + chunk) * D1 + c0;
  Sy_ex[sidx] = sy0; Sy_ex[sidx + 1] = sy1;
  SG_ex[sidx] = sg0; SG_ex[sidx + 1] = sg1;
}

// ---------------- chunk-state scan (phase B) -------------------------------
// entry(k+1) = local_exit(k) + homogeneous fixup from entry(k), L = CLEN.
__global__ __launch_bounds__(256) void state_scan(const float* __restrict__ Sy_ex,
                                                  const float* __restrict__ SG_ex,
                                                  float* __restrict__ Sy_in,
                                                  float* __restrict__ SG_in) {
  int idx = blockIdx.x * 256 + threadIdx.x;   // z*2048 + c, total 4*2048
  if (idx >= 4 * D1) return;
  int z = idx >> 11, c = idx & (D1 - 1);
  float ey = 0.f, eg = 0.f;
  for (int k = 0; k < NCHUNK; ++k) {
    size_t s = ((size_t)z * NCHUNK + k) * D1 + c;
    Sy_in[s] = ey; SG_in[s] = eg;
    float lex = Sy_ex[s], lgx = SG_ex[s];
    ey = lex + G_CL * (ey + (float)CLEN * eg);
    eg = lgx + G_CL * eg;
  }
}

// ---------------- combine + gate (phase C), 2 channels/thread --------------
// y = [y+loc + g^Dp (y_in + Dp G_in)] + [y-loc + g^Dn (...)] + tz*V;  g = U*y
__global__ __launch_bounds__(256) void combine_kernel(const unsigned short* __restrict__ ypl,
                                                      const unsigned short* __restrict__ ynl,
                                                      const unsigned short* __restrict__ Vp,
                                                      const float* __restrict__ Sy_in,
                                                      const float* __restrict__ SG_in,
                                                      const float* __restrict__ tz,
                                                      const unsigned short* __restrict__ U,
                                                      unsigned short* __restrict__ G) {
  int e = blockIdx.x * 256 + threadIdx.x;     // pair index over [b][t][c/2]
  int cp = e & (D1 / 2 - 1);
  int c0 = cp * 2;
  int r = e >> 10;
  int t = r & (NSEQ - 1);
  int b = r >> 11;
  int kp = t >> 5;  float dpD = (float)((t & 31) + 1);
  int tau = (NSEQ - 1) - t;
  int kn = tau >> 5; float dnD = (float)((tau & 31) + 1);
  float gp = __expf(dpD * LN_G);
  float gn = __expf(dnD * LN_G);
  size_t ix = (size_t)r * D1 + c0;
  size_t sp = ((size_t)(b) * NCHUNK + kp) * D1 + c0;          // z = b (pos)
  size_t sn = ((size_t)(2 + b) * NCHUNK + kn) * D1 + c0;      // z = 2+b (neg)
  unsigned int pyl = *(const unsigned int*)(ypl + ix);
  unsigned int pyn = *(const unsigned int*)(ynl + ix);
  unsigned int pv  = *(const unsigned int*)(Vp + ((size_t)b * VPROWS + 2048 + t) * D1 + c0);
  unsigned int pu  = *(const unsigned int*)(U + ix);
  float2 syp = *(const float2*)(Sy_in + sp);
  float2 sgp = *(const float2*)(SG_in + sp);
  float2 syn = *(const float2*)(Sy_in + sn);
  float2 sgn = *(const float2*)(SG_in + sn);
  float2 tzv = *(const float2*)(tz + c0);
  float y0 = bf2f((unsigned short)(pyl & 0xffffu)) + gp * (syp.x + dpD * sgp.x)
           + bf2f((unsigned short)(pyn & 0xffffu)) + gn * (syn.x + dnD * sgn.x)
           + tzv.x * bf2f((unsigned short)(pv & 0xffffu));
  float y1 = bf2f((unsigned short)(pyl >> 16)) + gp * (syp.y + dpD * sgp.y)
           + bf2f((unsigned short)(pyn >> 16)) + gn * (syn.y + dnD * sgn.y)
           + tzv.y * bf2f((unsigned short)(pv >> 16));
  float g0 = bf2f((unsigned short)(pu & 0xffffu)) * y0;
  float g1 = bf2f((unsigned short)(pu >> 16)) * y1;
  *(unsigned int*)(G + ix) = (unsigned int)f2bf(g0) | ((unsigned int)f2bf(g1) << 16);
}

// ---------------------------------------------------------------------------
extern "C" void kernel_launch(void* const* d_in, const int* in_sizes, int n_in,
                              void* d_out, int out_size, void* d_ws, size_t ws_size,
                              hipStream_t stream) {
  const float* x      = (const float*)d_in[0];
  const float* Wu     = (const float*)d_in[1];
  const float* bu     = (const float*)d_in[2];
  const float* Wv     = (const float*)d_in[3];
  const float* bv     = (const float*)d_in[4];
  const float* Wo     = (const float*)d_in[5];
  const float* bo     = (const float*)d_in[6];
  const float* a_pos  = (const float*)d_in[7];
  const float* b_pos  = (const float*)d_in[8];
  const float* a_neg  = (const float*)d_in[9];
  const float* b_neg  = (const float*)d_in[10];
  const float* t_zero = (const float*)d_in[11];
  float* out = (float*)d_out;

  char* ws = (char*)d_ws;
  unsigned short* x_bf  = (unsigned short*)ws; ws += (size_t)MROWS * DM * 2;        //  8 MB
  unsigned short* u_ws  = (unsigned short*)ws; ws += (size_t)MROWS * D1 * 2;        // 16 MB (g in-place)
  unsigned short* Vp    = (unsigned short*)ws; ws += (size_t)BB * VPROWS * D1 * 2;  // 48 MB padded V
  unsigned short* ypl   = (unsigned short*)ws; ws += (size_t)MROWS * D1 * 2;        // 16 MB
  unsigned short* ynl   = (unsigned short*)ws; ws += (size_t)MROWS * D1 * 2;        // 16 MB
  float* dtp   = (float*)ws; ws += (size_t)H * NTAP * HD * 4;                       // 229 KB
  float* dtn   = (float*)ws; ws += (size_t)H * NTAP * HD * 4;
  float* Sy_ex = (float*)ws; ws += (size_t)4 * NCHUNK * D1 * 4;                     // 2 MB each
  float* SG_ex = (float*)ws; ws += (size_t)4 * NCHUNK * D1 * 4;
  float* Sy_in = (float*)ws; ws += (size_t)4 * NCHUNK * D1 * 4;
  float* SG_in = (float*)ws; ws += (size_t)4 * NCHUNK * D1 * 4;
  // weight buffers alias ypl/ynl (disjoint lifetimes, stream-ordered):
  //   WT2 [4096][1024] bf16 (8 MB) used only by the fused uv-gemm (before scan)
  //   WoT [1024][2048] bf16 (4 MB) written after combine, read by out-gemm
  unsigned short* WT2 = ypl;
  unsigned short* WoT = ypl;

  dim3 tb256(256);
  dim3 tptb(32, 8);
  // zero the V pads (rows [0,2048) and [4096,6144) per b)
  (void)hipMemsetAsync(Vp, 0, (size_t)2048 * D1 * 2, stream);
  (void)hipMemsetAsync(Vp + (size_t)4096 * D1, 0, (size_t)2048 * D1 * 2, stream);
  (void)hipMemsetAsync(Vp + (size_t)VPROWS * D1, 0, (size_t)2048 * D1 * 2, stream);
  (void)hipMemsetAsync(Vp + ((size_t)VPROWS + 4096) * D1, 0, (size_t)2048 * D1 * 2, stream);
  // x -> bf16
  cvt_kernel<<<dim3((MROWS * DM / 4 + 255) / 256), tb256, 0, stream>>>(x, x_bf, MROWS * DM / 4);
  // low-rank kernel factors -> sparse delta tables (fused, both dirs)
  kdtab_kernel<<<dim3(H, 2), tb256, 0, stream>>>(a_pos, b_pos, a_neg, b_neg, dtp, dtn);
  // fused u|v gemm: Bt = [WuT ; WvT]  (N = 4096)
  tpc_kernel<<<dim3(D1 / 32, DM / 32), tptb, 0, stream>>>(Wu, WT2, DM, D1);
  tpc_kernel<<<dim3(D1 / 32, DM / 32), tptb, 0, stream>>>(Wv, WT2 + (size_t)D1 * DM, DM, D1);
  gemm_bf16<<<dim3(2 * D1 / 128, MROWS / 128), tb256, 0, stream>>>(
      x_bf, WT2, bu, bv, u_ws, Vp, MROWS, 2 * D1, DM, 1, 0, 1);
  // IIR conv: chunked scans -> state scan -> combine+gate (in-place over u)
  scan_chunks<<<dim3(D1 / 512, NCHUNK, 4), tb256, 0, stream>>>(Vp, dtp, dtn, ypl, ynl, Sy_ex, SG_ex);
  state_scan<<<dim3((4 * D1 + 255) / 256), tb256, 0, stream>>>(Sy_ex, SG_ex, Sy_in, SG_in);
  combine_kernel<<<dim3((size_t)MROWS * D1 / 512), tb256, 0, stream>>>(ypl, ynl, Vp, Sy_in, SG_in, t_zero, u_ws, u_ws);
  // out = g @ Wo + bo (fp32)
  tpc_kernel<<<dim3(DM / 32, D1 / 32), tptb, 0, stream>>>(Wo, WoT, D1, DM);
  gemm_bf16<<<dim3(DM / 128, MROWS / 128), tb256, 0, stream>>>(
      u_ws, WoT, bo, bo, out, out, MROWS, DM, D1, 0, 1, 0);
}

// Round 8
// 336.749 us; speedup vs baseline: 2.0498x; 1.0284x over previous
//
#include <hip/hip_runtime.h>
#include <hip/hip_bf16.h>
#include <stdint.h>
#include <stddef.h>

// Problem constants (fixed by the reference)
#define BB 2
#define NSEQ 2048
#define DM 1024
#define H 16
#define HD 128
#define D1 2048
#define NKI 16
#define RANKI 32
#define MROWS (BB * NSEQ)   // 4096 rows for all GEMMs
#define VPROWS 6144         // 2048 zero-pad | 2048 data | 2048 zero-pad
#define NTAP 28
#define NPAIR 13
#define NCHUNK 64
#define CLEN 32
#define GAMMA_F 0.999f
#define G_CL 0.9684910f     // 0.999^32 (chunk-length homogeneous decay)
// ln(0.999), for gamma^x = exp(x*ln_g)  (__exp2f collides with glibc; __expf is safe)
#define LN_G (-1.00050033e-3f)

// Sparse-tap positions of delta = (1 - g z)^2 * K  (K piecewise-linear * g^l,
// knots at l = 1 + 136.4j; integer knots j=5 (683), j=10 (1365) give 1 tap).
__device__ constexpr int TAPS[NTAP] = {
  1, 2, 138, 139, 274, 275, 411, 412, 547, 548, 684,
  820, 821, 956, 957, 1093, 1094, 1229, 1230, 1366,
  1502, 1503, 1638, 1639, 1775, 1776, 1911, 1912};
// pair decomposition: 13 (lead l, lag l+1) pairs + 2 singletons (684, 1366).
// lag value at step i == lead value at step i-1 -> register carry.
__device__ constexpr int LEADL[NPAIR] = {1, 138, 274, 411, 547, 820, 956, 1093, 1229, 1502, 1638, 1775, 1911};
__device__ constexpr int LEADI[NPAIR] = {0, 2, 4, 6, 8, 11, 13, 15, 17, 20, 22, 24, 26};
#define SGL0_L 684
#define SGL0_I 10
#define SGL1_L 1366
#define SGL1_I 19

typedef short short8 __attribute__((ext_vector_type(8)));
typedef float floatx4 __attribute__((ext_vector_type(4)));

__device__ __forceinline__ float bf2f(unsigned short u) {
  union { unsigned int i; float f; } v; v.i = ((unsigned int)u) << 16; return v.f;
}
__device__ __forceinline__ unsigned short f2bf(float f) {
  union { float f; unsigned int i; } v; v.f = f;
  unsigned int r = (v.i + 0x7FFFu + ((v.i >> 16) & 1u)) >> 16;
  return (unsigned short)r;
}
// async 16B global->LDS DMA: lane i lands at (wave-uniform) l + i*16 bytes
__device__ __forceinline__ void async16(const unsigned short* g, unsigned short* l) {
  __builtin_amdgcn_global_load_lds(
      (const __attribute__((address_space(1))) unsigned int*)g,
      (__attribute__((address_space(3))) unsigned int*)l, 16, 0, 0);
}

// ---------------- fp32 -> bf16 elementwise convert (vectorized) ------------
__global__ __launch_bounds__(256) void cvt_kernel(const float* __restrict__ in,
                                                  unsigned short* __restrict__ out,
                                                  int n4) {
  int i = blockIdx.x * 256 + threadIdx.x;
  if (i >= n4) return;
  float4 f = ((const float4*)in)[i];
  ushort4 o;
  o.x = f2bf(f.x); o.y = f2bf(f.y); o.z = f2bf(f.z); o.w = f2bf(f.w);
  ((ushort4*)out)[i] = o;
}

// ------- fused transpose+convert: out_bf16[c][r] = in_f32[r][c] ------------
__global__ __launch_bounds__(256) void tpc_kernel(const float* __restrict__ in,
                                                  unsigned short* __restrict__ out,
                                                  int rows, int cols) {
  __shared__ unsigned short t[32][33];
  int bx = blockIdx.x * 32, by = blockIdx.y * 32;
  int tx = threadIdx.x, ty = threadIdx.y; // blockDim = (32,8)
#pragma unroll
  for (int j = 0; j < 32; j += 8)
    t[ty + j][tx] = f2bf(in[(size_t)(by + ty + j) * cols + bx + tx]);
  __syncthreads();
#pragma unroll
  for (int j = 0; j < 32; j += 8)
    out[(size_t)(bx + ty + j) * rows + by + tx] = t[tx][ty + j];
}

// ---- K(l) = interp(kind, l) * gamma^l on an LDS copy of kind --------------
__device__ __forceinline__ float KinterpL(const float* kk, int l, int d) {
  if (l < 1) return 0.0f;   // l > 2047 never queried (max tap 1912)
  float p = (float)(l - 1) * (15.0f / 2046.0f);
  int lo = (int)p; if (lo > 15) lo = 15;
  int hi = lo + 1; if (hi > 15) hi = 15;
  float w = p - (float)lo;
  float v = kk[lo * HD + d] * (1.0f - w) + kk[hi * HD + d] * w;
  return v * __powf(GAMMA_F, (float)l);
}

// ---- fused: kind = a@b per (head,dir) -> delta table (1-gz)^2 K at taps ---
__global__ __launch_bounds__(256) void kdtab_kernel(const float* __restrict__ ap,
                                                    const float* __restrict__ bp,
                                                    const float* __restrict__ an,
                                                    const float* __restrict__ bn,
                                                    float* __restrict__ dtp,
                                                    float* __restrict__ dtn) {
  __shared__ float kk[NKI * HD];  // 8 KB
  int h = blockIdx.x, dir = blockIdx.y;
  const float* a = (dir ? an : ap) + h * NKI * RANKI;
  const float* b = (dir ? bn : bp) + h * RANKI * HD;
  for (int e = threadIdx.x; e < NKI * HD; e += 256) {
    int k = e >> 7, d = e & 127;
    float s = 0.0f;
#pragma unroll
    for (int r = 0; r < RANKI; ++r) s += a[k * RANKI + r] * b[r * HD + d];
    kk[e] = s;
  }
  __syncthreads();
  float* dt = (dir ? dtn : dtp) + (size_t)h * NTAP * HD;
  for (int e = threadIdx.x; e < NTAP * HD; e += 256) {
    int j = e >> 7, d = e & 127;
    int l = TAPS[j];
    float K0 = KinterpL(kk, l, d);
    float K1 = KinterpL(kk, l - 1, d);
    float K2 = KinterpL(kk, l - 2, d);
    dt[e] = K0 - 2.0f * GAMMA_F * K1 + (GAMMA_F * GAMMA_F) * K2;
  }
}

// ---------------- bf16 MFMA GEMM, double-buffered LDS ----------------------
// C = [silu](A @ Bt^T + bias). 128x128 tile, BK=32, global_load_lds width=16.
// uv_mode: N=4096 fused u|v; n<2048 -> C (u), n>=2048 -> C2 (Vp, row-remapped).
__global__ __launch_bounds__(256) void gemm_bf16(const unsigned short* __restrict__ A,
                                                 const unsigned short* __restrict__ Bt,
                                                 const float* __restrict__ bias,
                                                 const float* __restrict__ bias2,
                                                 void* __restrict__ C,
                                                 void* __restrict__ C2,
                                                 int M, int N, int K,
                                                 int do_silu, int c_fp32, int uv_mode) {
  __shared__ unsigned short Al[2][128 * 32];   // 2 x 8 KB
  __shared__ unsigned short Bl[2][128 * 32];   // 2 x 8 KB
  int m0 = blockIdx.y * 128, n0 = blockIdx.x * 128;
  int tid = threadIdx.x;
  int lane = tid & 63, w = tid >> 6;
  int rw = (w >> 1) * 64, cw = (w & 1) * 64;
  int q = lane >> 4, l16 = lane & 15;
  floatx4 acc[4][4];
#pragma unroll
  for (int mt = 0; mt < 4; ++mt)
#pragma unroll
    for (int nt = 0; nt < 4; ++nt) acc[mt][nt] = (floatx4){0.f, 0.f, 0.f, 0.f};
  int grow = tid >> 2;            // row 0..63 within a 64-row segment
  int gcol = (tid & 3) * 8;       // k-offset (elems)
  const unsigned short* A0 = A + (size_t)(m0 + grow) * K + gcol;
  const unsigned short* A1 = A0 + (size_t)64 * K;
  const unsigned short* B0 = Bt + (size_t)(n0 + grow) * K + gcol;
  const unsigned short* B1 = B0 + (size_t)64 * K;
  int woff = w * 512;             // wave-uniform LDS element base
  int nIter = K >> 5;
  // prologue: stage iter 0 into buffer 0
  async16(A0, &Al[0][woff]);
  async16(A1, &Al[0][2048 + woff]);
  async16(B0, &Bl[0][woff]);
  async16(B1, &Bl[0][2048 + woff]);
  int p = 0;
  for (int i = 0; i < nIter; ++i) {
    __syncthreads();   // drains vmcnt: buffer p staged; prev reads of p^1 done
    if (i + 1 < nIter) {           // prefetch i+1 into p^1, overlaps MFMA below
      int kn = (i + 1) << 5;
      async16(A0 + kn, &Al[p ^ 1][woff]);
      async16(A1 + kn, &Al[p ^ 1][2048 + woff]);
      async16(B0 + kn, &Bl[p ^ 1][woff]);
      async16(B1 + kn, &Bl[p ^ 1][2048 + woff]);
    }
    short8 af[4], bfr[4];
#pragma unroll
    for (int i4 = 0; i4 < 4; ++i4) {
      af[i4]  = *(const short8*)(&Al[p][(rw + i4 * 16 + l16) * 32 + q * 8]);
      bfr[i4] = *(const short8*)(&Bl[p][(cw + i4 * 16 + l16) * 32 + q * 8]);
    }
#pragma unroll
    for (int mt = 0; mt < 4; ++mt)
#pragma unroll
      for (int nt = 0; nt < 4; ++nt)
        acc[mt][nt] = __builtin_amdgcn_mfma_f32_16x16x32_bf16(af[mt], bfr[nt], acc[mt][nt], 0, 0, 0);
    p ^= 1;
  }
  // epilogue: D[row = q*4 + r][col = lane&15] per 16x16 tile (verified mapping)
  int isv = uv_mode && (n0 >= 2048);
  int ldc = uv_mode ? 2048 : N;
  int ncb = isv ? (n0 - 2048) : n0;
  const float* buse = isv ? bias2 : bias;
#pragma unroll
  for (int mt = 0; mt < 4; ++mt) {
#pragma unroll
    for (int nt = 0; nt < 4; ++nt) {
      int n = ncb + cw + nt * 16 + l16;
      float bsv = buse[n];
#pragma unroll
      for (int r = 0; r < 4; ++r) {
        int m = m0 + rw + mt * 16 + q * 4 + r;
        float val = acc[mt][nt][r] + bsv;
        if (do_silu) val = val / (1.0f + __expf(-val));
        if (isv) {
          size_t mrow = (size_t)(2048 + m + ((m >> 11) << 12));  // padded-V row
          ((unsigned short*)C2)[mrow * 2048 + n] = f2bf(val);
        } else if (c_fp32) {
          ((float*)C)[(size_t)m * ldc + n] = val;
        } else {
          ((unsigned short*)C)[(size_t)m * ldc + n] = f2bf(val);
        }
      }
    }
  }
}

// ---------------- chunked IIR scan (phase A) -------------------------------
// Per (dir, b, chunk, c-pair): zero-state local scan of CLEN steps.
//   F[t] = sum_j delta[h,j,d] * Vp[b, 2048 + t -/+ l_j, c]   (pads are zero)
// delta staged in LDS (off the VMEM pipe); lag taps (l+1) reuse lead-tap (l)
// values from the previous step via register carries: 15 V-loads/step not 28.
__global__ __launch_bounds__(256) void scan_chunks(const unsigned short* __restrict__ Vp,
                                                   const float* __restrict__ dp,
                                                   const float* __restrict__ dn,
                                                   unsigned short* __restrict__ ypl,
                                                   unsigned short* __restrict__ ynl,
                                                   float* __restrict__ Sy_ex,
                                                   float* __restrict__ SG_ex) {
  __shared__ float dsh[NTAP][512];   // 57344 B: delta for this block's 512 ch
  int z = blockIdx.z;            // dir*2 + b
  int dir = z >> 1, b = z & 1;
  int chunk = blockIdx.y;
  int cBase = blockIdx.x * 512;
  int tid = threadIdx.x;
  {
    const float* dt = dir ? dn : dp;
    for (int e = tid; e < NTAP * 512; e += 256) {
      int j = e >> 9, cl = e & 511;
      int c = cBase + cl, h = c >> 7, d = c & 127;
      dsh[j][cl] = dt[((size_t)h * NTAP + j) * HD + d];
    }
  }
  __syncthreads();
  int c0 = cBase + tid * 2;      // two channels per thread
  int cl0 = tid * 2;
  const unsigned short* Vb = Vp + (size_t)b * VPROWS * D1 + c0;
  unsigned short* yl = (dir ? ynl : ypl) + (size_t)b * NSEQ * D1 + c0;
  float sy0 = 0.f, sy1 = 0.f, sg0 = 0.f, sg1 = 0.f;
  float carry0[NPAIR], carry1[NPAIR];
  if (!dir) {
    int t0 = chunk * CLEN;
    const unsigned short* Vrow = Vb + (size_t)(2048 + t0) * D1;
    // prime carries with step -1 lead values: row t0-1-l  (pad rows are zero)
#pragma unroll
    for (int p = 0; p < NPAIR; ++p) {
      unsigned int pk = *(const unsigned int*)(Vrow - (ptrdiff_t)(LEADL[p] + 1) * D1);
      carry0[p] = bf2f((unsigned short)(pk & 0xffffu));
      carry1[p] = bf2f((unsigned short)(pk >> 16));
    }
    int t = t0;
    for (int i = 0; i < CLEN; ++i) {
      float F0 = 0.f, F1 = 0.f;
#pragma unroll
      for (int p = 0; p < NPAIR; ++p) {
        unsigned int pk = *(const unsigned int*)(Vrow - (ptrdiff_t)LEADL[p] * D1);
        float vl0 = bf2f((unsigned short)(pk & 0xffffu));
        float vl1 = bf2f((unsigned short)(pk >> 16));
        float2 dl = *(const float2*)&dsh[LEADI[p]][cl0];
        float2 dg = *(const float2*)&dsh[LEADI[p] + 1][cl0];
        F0 += dl.x * vl0 + dg.x * carry0[p];
        F1 += dl.y * vl1 + dg.y * carry1[p];
        carry0[p] = vl0; carry1[p] = vl1;
      }
      {
        unsigned int pk = *(const unsigned int*)(Vrow - (ptrdiff_t)SGL0_L * D1);
        float2 ds = *(const float2*)&dsh[SGL0_I][cl0];
        F0 += ds.x * bf2f((unsigned short)(pk & 0xffffu));
        F1 += ds.y * bf2f((unsigned short)(pk >> 16));
      }
      {
        unsigned int pk = *(const unsigned int*)(Vrow - (ptrdiff_t)SGL1_L * D1);
        float2 ds = *(const float2*)&dsh[SGL1_I][cl0];
        F0 += ds.x * bf2f((unsigned short)(pk & 0xffffu));
        F1 += ds.y * bf2f((unsigned short)(pk >> 16));
      }
      sg0 = GAMMA_F * sg0 + F0; sy0 = GAMMA_F * sy0 + sg0;
      sg1 = GAMMA_F * sg1 + F1; sy1 = GAMMA_F * sy1 + sg1;
      unsigned int pack = (unsigned int)f2bf(sy0) | ((unsigned int)f2bf(sy1) << 16);
      *(unsigned int*)(yl + (size_t)(t + i) * D1) = pack;
      Vrow += D1;
    }
  } else {
    int tstart = (NSEQ - 1) - chunk * CLEN;        // reversed time
    const unsigned short* Vrow = Vb + (size_t)(2048 + tstart) * D1;
#pragma unroll
    for (int p = 0; p < NPAIR; ++p) {
      unsigned int pk = *(const unsigned int*)(Vrow + (ptrdiff_t)(LEADL[p] + 1) * D1);
      carry0[p] = bf2f((unsigned short)(pk & 0xffffu));
      carry1[p] = bf2f((unsigned short)(pk >> 16));
    }
    for (int i = 0; i < CLEN; ++i) {
      float F0 = 0.f, F1 = 0.f;
#pragma unroll
      for (int p = 0; p < NPAIR; ++p) {
        unsigned int pk = *(const unsigned int*)(Vrow + (ptrdiff_t)LEADL[p] * D1);
        float vl0 = bf2f((unsigned short)(pk & 0xffffu));
        float vl1 = bf2f((unsigned short)(pk >> 16));
        float2 dl = *(const float2*)&dsh[LEADI[p]][cl0];
        float2 dg = *(const float2*)&dsh[LEADI[p] + 1][cl0];
        F0 += dl.x * vl0 + dg.x * carry0[p];
        F1 += dl.y * vl1 + dg.y * carry1[p];
        carry0[p] = vl0; carry1[p] = vl1;
      }
      {
        unsigned int pk = *(const unsigned int*)(Vrow + (ptrdiff_t)SGL0_L * D1);
        float2 ds = *(const float2*)&dsh[SGL0_I][cl0];
        F0 += ds.x * bf2f((unsigned short)(pk & 0xffffu));
        F1 += ds.y * bf2f((unsigned short)(pk >> 16));
      }
      {
        unsigned int pk = *(const unsigned int*)(Vrow + (ptrdiff_t)SGL1_L * D1);
        float2 ds = *(const float2*)&dsh[SGL1_I][cl0];
        F0 += ds.x * bf2f((unsigned short)(pk & 0xffffu));
        F1 += ds.y * bf2f((unsigned short)(pk >> 16));
      }
      sg0 = GAMMA_F * sg0 + F0; sy0 = GAMMA_F * sy0 + sg0;
      sg1 = GAMMA_F * sg1 + F1; sy1 = GAMMA_F * sy1 + sg1;
      unsigned int pack = (unsigned int)f2bf(sy0) | ((unsigned int)f2bf(sy1) << 16);
      *(unsigned int*)(yl + (size_t)(tstart - i) * D1) = pack;
      Vrow -= D1;
    }
  }
  size_t sidx = ((size_t)z * NCHUNK + chunk) * D1 + c0;
  Sy_ex[sidx] = sy0; Sy_ex[sidx + 1] = sy1;
  SG_ex[sidx] = sg0; SG_ex[sidx + 1] = sg1;
}

// ---------------- chunk-state scan (phase B) -------------------------------
// entry(k+1) = local_exit(k) + homogeneous fixup from entry(k), L = CLEN.
__global__ __launch_bounds__(256) void state_scan(const float* __restrict__ Sy_ex,
                                                  const float* __restrict__ SG_ex,
                                                  float* __restrict__ Sy_in,
                                                  float* __restrict__ SG_in) {
  int idx = blockIdx.x * 256 + threadIdx.x;   // z*2048 + c, total 4*2048
  if (idx >= 4 * D1) return;
  int z = idx >> 11, c = idx & (D1 - 1);
  float ey = 0.f, eg = 0.f;
  for (int k = 0; k < NCHUNK; ++k) {
    size_t s = ((size_t)z * NCHUNK + k) * D1 + c;
    Sy_in[s] = ey; SG_in[s] = eg;
    float lex = Sy_ex[s], lgx = SG_ex[s];
    ey = lex + G_CL * (ey + (float)CLEN * eg);
    eg = lgx + G_CL * eg;
  }
}

// ---------------- combine + gate (phase C), 4 channels/thread --------------
// y = [y+loc + g^Dp (y_in + Dp G_in)] + [y-loc + g^Dn (...)] + tz*V;  g = U*y
__global__ __launch_bounds__(256) void combine_kernel(const unsigned short* __restrict__ ypl,
                                                      const unsigned short* __restrict__ ynl,
                                                      const unsigned short* __restrict__ Vp,
                                                      const float* __restrict__ Sy_in,
                                                      const float* __restrict__ SG_in,
                                                      const float* __restrict__ tz,
                                                      const unsigned short* __restrict__ U,
                                                      unsigned short* __restrict__ G) {
  int e = blockIdx.x * 256 + threadIdx.x;     // quad index over [b][t][c/4]
  int cq = e & (D1 / 4 - 1);
  int c0 = cq * 4;
  int r = e >> 9;
  int t = r & (NSEQ - 1);
  int b = r >> 11;
  int kp = t >> 5;  float dpD = (float)((t & 31) + 1);
  int tau = (NSEQ - 1) - t;
  int kn = tau >> 5; float dnD = (float)((tau & 31) + 1);
  float gp = __expf(dpD * LN_G);
  float gn = __expf(dnD * LN_G);
  size_t ix = (size_t)r * D1 + c0;
  size_t sp = ((size_t)(b) * NCHUNK + kp) * D1 + c0;          // z = b (pos)
  size_t sn = ((size_t)(2 + b) * NCHUNK + kn) * D1 + c0;      // z = 2+b (neg)
  uint2 pyl = *(const uint2*)(ypl + ix);
  uint2 pyn = *(const uint2*)(ynl + ix);
  uint2 pv  = *(const uint2*)(Vp + ((size_t)b * VPROWS + 2048 + t) * D1 + c0);
  uint2 pu  = *(const uint2*)(U + ix);
  float4 syp = *(const float4*)(Sy_in + sp);
  float4 sgp = *(const float4*)(SG_in + sp);
  float4 syn = *(const float4*)(Sy_in + sn);
  float4 sgn = *(const float4*)(SG_in + sn);
  float4 tzv = *(const float4*)(tz + c0);
  float yv[4], uv[4], vv[4];
  yv[0] = bf2f((unsigned short)(pyl.x & 0xffffu)) + gp * (syp.x + dpD * sgp.x)
        + bf2f((unsigned short)(pyn.x & 0xffffu)) + gn * (syn.x + dnD * sgn.x);
  yv[1] = bf2f((unsigned short)(pyl.x >> 16)) + gp * (syp.y + dpD * sgp.y)
        + bf2f((unsigned short)(pyn.x >> 16)) + gn * (syn.y + dnD * sgn.y);
  yv[2] = bf2f((unsigned short)(pyl.y & 0xffffu)) + gp * (syp.z + dpD * sgp.z)
        + bf2f((unsigned short)(pyn.y & 0xffffu)) + gn * (syn.z + dnD * sgn.z);
  yv[3] = bf2f((unsigned short)(pyl.y >> 16)) + gp * (syp.w + dpD * sgp.w)
        + bf2f((unsigned short)(pyn.y >> 16)) + gn * (syn.w + dnD * sgn.w);
  vv[0] = bf2f((unsigned short)(pv.x & 0xffffu)); vv[1] = bf2f((unsigned short)(pv.x >> 16));
  vv[2] = bf2f((unsigned short)(pv.y & 0xffffu)); vv[3] = bf2f((unsigned short)(pv.y >> 16));
  uv[0] = bf2f((unsigned short)(pu.x & 0xffffu)); uv[1] = bf2f((unsigned short)(pu.x >> 16));
  uv[2] = bf2f((unsigned short)(pu.y & 0xffffu)); uv[3] = bf2f((unsigned short)(pu.y >> 16));
  float tza[4] = {tzv.x, tzv.y, tzv.z, tzv.w};
  uint2 og;
  unsigned short g0 = f2bf(uv[0] * (yv[0] + tza[0] * vv[0]));
  unsigned short g1 = f2bf(uv[1] * (yv[1] + tza[1] * vv[1]));
  unsigned short g2 = f2bf(uv[2] * (yv[2] + tza[2] * vv[2]));
  unsigned short g3 = f2bf(uv[3] * (yv[3] + tza[3] * vv[3]));
  og.x = (unsigned int)g0 | ((unsigned int)g1 << 16);
  og.y = (unsigned int)g2 | ((unsigned int)g3 << 16);
  *(uint2*)(G + ix) = og;
}

// ---------------------------------------------------------------------------
extern "C" void kernel_launch(void* const* d_in, const int* in_sizes, int n_in,
                              void* d_out, int out_size, void* d_ws, size_t ws_size,
                              hipStream_t stream) {
  const float* x      = (const float*)d_in[0];
  const float* Wu     = (const float*)d_in[1];
  const float* bu     = (const float*)d_in[2];
  const float* Wv     = (const float*)d_in[3];
  const float* bv     = (const float*)d_in[4];
  const float* Wo     = (const float*)d_in[5];
  const float* bo     = (const float*)d_in[6];
  const float* a_pos  = (const float*)d_in[7];
  const float* b_pos  = (const float*)d_in[8];
  const float* a_neg  = (const float*)d_in[9];
  const float* b_neg  = (const float*)d_in[10];
  const float* t_zero = (const float*)d_in[11];
  float* out = (float*)d_out;

  char* ws = (char*)d_ws;
  unsigned short* x_bf  = (unsigned short*)ws; ws += (size_t)MROWS * DM * 2;        //  8 MB
  unsigned short* u_ws  = (unsigned short*)ws; ws += (size_t)MROWS * D1 * 2;        // 16 MB (g in-place)
  unsigned short* Vp    = (unsigned short*)ws; ws += (size_t)BB * VPROWS * D1 * 2;  // 48 MB padded V
  unsigned short* ypl   = (unsigned short*)ws; ws += (size_t)MROWS * D1 * 2;        // 16 MB
  unsigned short* ynl   = (unsigned short*)ws; ws += (size_t)MROWS * D1 * 2;        // 16 MB
  float* dtp   = (float*)ws; ws += (size_t)H * NTAP * HD * 4;                       // 229 KB
  float* dtn   = (float*)ws; ws += (size_t)H * NTAP * HD * 4;
  float* Sy_ex = (float*)ws; ws += (size_t)4 * NCHUNK * D1 * 4;                     // 2 MB each
  float* SG_ex = (float*)ws; ws += (size_t)4 * NCHUNK * D1 * 4;
  float* Sy_in = (float*)ws; ws += (size_t)4 * NCHUNK * D1 * 4;
  float* SG_in = (float*)ws; ws += (size_t)4 * NCHUNK * D1 * 4;
  // weight buffers alias ypl (disjoint lifetimes, stream-ordered)
  unsigned short* WT2 = ypl;
  unsigned short* WoT = ypl;

  dim3 tb256(256);
  dim3 tptb(32, 8);
  // zero the V pads (rows [0,2048) and [4096,6144) per b)
  (void)hipMemsetAsync(Vp, 0, (size_t)2048 * D1 * 2, stream);
  (void)hipMemsetAsync(Vp + (size_t)4096 * D1, 0, (size_t)2048 * D1 * 2, stream);
  (void)hipMemsetAsync(Vp + (size_t)VPROWS * D1, 0, (size_t)2048 * D1 * 2, stream);
  (void)hipMemsetAsync(Vp + ((size_t)VPROWS + 4096) * D1, 0, (size_t)2048 * D1 * 2, stream);
  // x -> bf16
  cvt_kernel<<<dim3((MROWS * DM / 4 + 255) / 256), tb256, 0, stream>>>(x, x_bf, MROWS * DM / 4);
  // low-rank kernel factors -> sparse delta tables (fused, both dirs)
  kdtab_kernel<<<dim3(H, 2), tb256, 0, stream>>>(a_pos, b_pos, a_neg, b_neg, dtp, dtn);
  // fused u|v gemm: Bt = [WuT ; WvT]  (N = 4096)
  tpc_kernel<<<dim3(D1 / 32, DM / 32), tptb, 0, stream>>>(Wu, WT2, DM, D1);
  tpc_kernel<<<dim3(D1 / 32, DM / 32), tptb, 0, stream>>>(Wv, WT2 + (size_t)D1 * DM, DM, D1);
  gemm_bf16<<<dim3(2 * D1 / 128, MROWS / 128), tb256, 0, stream>>>(
      x_bf, WT2, bu, bv, u_ws, Vp, MROWS, 2 * D1, DM, 1, 0, 1);
  // IIR conv: chunked scans -> state scan -> combine+gate (in-place over u)
  scan_chunks<<<dim3(D1 / 512, NCHUNK, 4), tb256, 0, stream>>>(Vp, dtp, dtn, ypl, ynl, Sy_ex, SG_ex);
  state_scan<<<dim3((4 * D1 + 255) / 256), tb256, 0, stream>>>(Sy_ex, SG_ex, Sy_in, SG_in);
  combine_kernel<<<dim3((size_t)MROWS * D1 / 1024), tb256, 0, stream>>>(ypl, ynl, Vp, Sy_in, SG_in, t_zero, u_ws, u_ws);
  // out = g @ Wo + bo (fp32)
  tpc_kernel<<<dim3(DM / 32, D1 / 32), tptb, 0, stream>>>(Wo, WoT, D1, DM);
  gemm_bf16<<<dim3(DM / 128, MROWS / 128), tb256, 0, stream>>>(
      u_ws, WoT, bo, bo, out, out, MROWS, DM, D1, 0, 1, 0);
}

// Round 10
// 327.573 us; speedup vs baseline: 2.1072x; 1.0280x over previous
//
#include <hip/hip_runtime.h>
#include <hip/hip_bf16.h>
#include <stdint.h>
#include <stddef.h>

// Problem constants (fixed by the reference)
#define BB 2
#define NSEQ 2048
#define DM 1024
#define H 16
#define HD 128
#define D1 2048
#define NKI 16
#define RANKI 32
#define MROWS (BB * NSEQ)   // 4096 rows for all GEMMs
#define VPROWS 6144         // 2048 zero-pad | 2048 data | 2048 zero-pad
#define NTAP 28
#define NPAIR 13
#define NCHUNK 64
#define CLEN 32
#define GAMMA_F 0.999f
#define G_CL 0.9684910f     // 0.999^32 (chunk-length homogeneous decay)
// ln(0.999), for gamma^x = exp(x*ln_g)  (__exp2f collides with glibc; __expf is safe)
#define LN_G (-1.00050033e-3f)

// Sparse-tap positions of delta = (1 - g z)^2 * K  (K piecewise-linear * g^l,
// knots at l = 1 + 136.4j; integer knots j=5 (683), j=10 (1365) give 1 tap).
// NOTE: delta must remain fp32 everywhere — h[tau] = (tau+1)g^tau amplifies
// delta errors by up to ~368, so bf16 delta (rel err 2^-9) breaks the
// telescoping cancellation and yields O(10) output error [R9 failure].
__device__ constexpr int TAPS[NTAP] = {
  1, 2, 138, 139, 274, 275, 411, 412, 547, 548, 684,
  820, 821, 956, 957, 1093, 1094, 1229, 1230, 1366,
  1502, 1503, 1638, 1639, 1775, 1776, 1911, 1912};
// pair decomposition: 13 (lead l, lag l+1) pairs + 2 singletons (684, 1366).
// lag value at step i == lead value at step i-1 -> register carry.
__device__ constexpr int LEADL[NPAIR] = {1, 138, 274, 411, 547, 820, 956, 1093, 1229, 1502, 1638, 1775, 1911};
__device__ constexpr int LEADI[NPAIR] = {0, 2, 4, 6, 8, 11, 13, 15, 17, 20, 22, 24, 26};
#define SGL0_L 684
#define SGL0_I 10
#define SGL1_L 1366
#define SGL1_I 19

typedef short short8 __attribute__((ext_vector_type(8)));
typedef float floatx4 __attribute__((ext_vector_type(4)));

__device__ __forceinline__ float bf2f(unsigned short u) {
  union { unsigned int i; float f; } v; v.i = ((unsigned int)u) << 16; return v.f;
}
__device__ __forceinline__ unsigned short f2bf(float f) {
  union { float f; unsigned int i; } v; v.f = f;
  unsigned int r = (v.i + 0x7FFFu + ((v.i >> 16) & 1u)) >> 16;
  return (unsigned short)r;
}
// unpack a packed pair of bf16 (little-endian: low ushort = even channel)
__device__ __forceinline__ float bflo(unsigned int p) {
  union { unsigned int i; float f; } v; v.i = p << 16; return v.f;
}
__device__ __forceinline__ float bfhi(unsigned int p) {
  union { unsigned int i; float f; } v; v.i = p & 0xffff0000u; return v.f;
}
// async 16B global->LDS DMA: lane i lands at (wave-uniform) l + i*16 bytes
__device__ __forceinline__ void async16(const unsigned short* g, unsigned short* l) {
  __builtin_amdgcn_global_load_lds(
      (const __attribute__((address_space(1))) unsigned int*)g,
      (__attribute__((address_space(3))) unsigned int*)l, 16, 0, 0);
}

// ---------------- fp32 -> bf16 elementwise convert (vectorized) ------------
__global__ __launch_bounds__(256) void cvt_kernel(const float* __restrict__ in,
                                                  unsigned short* __restrict__ out,
                                                  int n4) {
  int i = blockIdx.x * 256 + threadIdx.x;
  if (i >= n4) return;
  float4 f = ((const float4*)in)[i];
  ushort4 o;
  o.x = f2bf(f.x); o.y = f2bf(f.y); o.z = f2bf(f.z); o.w = f2bf(f.w);
  ((ushort4*)out)[i] = o;
}

// ------- fused transpose+convert: out_bf16[c][r] = in_f32[r][c] ------------
__global__ __launch_bounds__(256) void tpc_kernel(const float* __restrict__ in,
                                                  unsigned short* __restrict__ out,
                                                  int rows, int cols) {
  __shared__ unsigned short t[32][33];
  int bx = blockIdx.x * 32, by = blockIdx.y * 32;
  int tx = threadIdx.x, ty = threadIdx.y; // blockDim = (32,8)
#pragma unroll
  for (int j = 0; j < 32; j += 8)
    t[ty + j][tx] = f2bf(in[(size_t)(by + ty + j) * cols + bx + tx]);
  __syncthreads();
#pragma unroll
  for (int j = 0; j < 32; j += 8)
    out[(size_t)(bx + ty + j) * rows + by + tx] = t[tx][ty + j];
}

// ---- K(l) = interp(kind, l) * gamma^l on an LDS copy of kind --------------
__device__ __forceinline__ float KinterpL(const float* kk, int l, int d) {
  if (l < 1) return 0.0f;   // l > 2047 never queried (max tap 1912)
  float p = (float)(l - 1) * (15.0f / 2046.0f);
  int lo = (int)p; if (lo > 15) lo = 15;
  int hi = lo + 1; if (hi > 15) hi = 15;
  float w = p - (float)lo;
  float v = kk[lo * HD + d] * (1.0f - w) + kk[hi * HD + d] * w;
  return v * __powf(GAMMA_F, (float)l);
}

// ---- fused: kind = a@b per (head,dir) -> fp32 delta table at taps ---------
__global__ __launch_bounds__(256) void kdtab_kernel(const float* __restrict__ ap,
                                                    const float* __restrict__ bp,
                                                    const float* __restrict__ an,
                                                    const float* __restrict__ bn,
                                                    float* __restrict__ dtp,
                                                    float* __restrict__ dtn) {
  __shared__ float kk[NKI * HD];  // 8 KB
  int h = blockIdx.x, dir = blockIdx.y;
  const float* a = (dir ? an : ap) + h * NKI * RANKI;
  const float* b = (dir ? bn : bp) + h * RANKI * HD;
  for (int e = threadIdx.x; e < NKI * HD; e += 256) {
    int k = e >> 7, d = e & 127;
    float s = 0.0f;
#pragma unroll
    for (int r = 0; r < RANKI; ++r) s += a[k * RANKI + r] * b[r * HD + d];
    kk[e] = s;
  }
  __syncthreads();
  float* dt = (dir ? dtn : dtp) + (size_t)h * NTAP * HD;
  for (int e = threadIdx.x; e < NTAP * HD; e += 256) {
    int j = e >> 7, d = e & 127;
    int l = TAPS[j];
    float K0 = KinterpL(kk, l, d);
    float K1 = KinterpL(kk, l - 1, d);
    float K2 = KinterpL(kk, l - 2, d);
    dt[e] = K0 - 2.0f * GAMMA_F * K1 + (GAMMA_F * GAMMA_F) * K2;
  }
}

// ---------------- bf16 MFMA GEMM, double-buffered LDS + XOR swizzle --------
// C = [silu](A @ Bt^T + bias). Tile = (MTILES*32) x 128, BK=32,
// global_load_lds width=16. LDS pos p of row r holds k-chunk p^(r&3)
// (staged via swizzled source addr) -> ds_read_b128 is 2-way max = free.
// uv_mode: N=4096 fused u|v; n<2048 -> C (u), n>=2048 -> C2 (Vp, row-remapped).
template <int MTILES>
__global__ __launch_bounds__(256) void gemm_bf16(const unsigned short* __restrict__ A,
                                                 const unsigned short* __restrict__ Bt,
                                                 const float* __restrict__ bias,
                                                 const float* __restrict__ bias2,
                                                 void* __restrict__ C,
                                                 void* __restrict__ C2,
                                                 int M, int N, int K,
                                                 int do_silu, int c_fp32, int uv_mode) {
  __shared__ unsigned short Al[2][MTILES * 1024];   // MTILES*32 rows x 32 elems
  __shared__ unsigned short Bl[2][4096];            // 128 rows x 32 elems
  int m0 = blockIdx.y * (MTILES * 32), n0 = blockIdx.x * 128;
  int tid = threadIdx.x;
  int lane = tid & 63, w = tid >> 6;
  int rw = (w >> 1) * (MTILES * 16), cw = (w & 1) * 64;
  int q = lane >> 4, l16 = lane & 15;
  floatx4 acc[MTILES][4];
#pragma unroll
  for (int mt = 0; mt < MTILES; ++mt)
#pragma unroll
    for (int nt = 0; nt < 4; ++nt) acc[mt][nt] = (floatx4){0.f, 0.f, 0.f, 0.f};
  int grow = tid >> 2;                           // row 0..63 within a segment
  int gcol = ((tid & 3) ^ ((tid >> 2) & 3)) * 8; // XOR-swizzled k-chunk
  const unsigned short* A0 = A + (size_t)(m0 + grow) * K + gcol;
  const unsigned short* A1 = A0 + (size_t)64 * K;
  const unsigned short* B0 = Bt + (size_t)(n0 + grow) * K + gcol;
  const unsigned short* B1 = B0 + (size_t)64 * K;
  int woff = w * 512;             // wave-uniform LDS element base
  int nIter = K >> 5;
  // prologue: stage iter 0 into buffer 0
  async16(A0, &Al[0][woff]);
  if (MTILES == 4) async16(A1, &Al[0][2048 + woff]);
  async16(B0, &Bl[0][woff]);
  async16(B1, &Bl[0][2048 + woff]);
  int p = 0;
  for (int i = 0; i < nIter; ++i) {
    __syncthreads();   // drains vmcnt: buffer p staged; prev reads of p^1 done
    if (i + 1 < nIter) {           // prefetch i+1 into p^1, overlaps MFMA below
      int kn = (i + 1) << 5;
      async16(A0 + kn, &Al[p ^ 1][woff]);
      if (MTILES == 4) async16(A1 + kn, &Al[p ^ 1][2048 + woff]);
      async16(B0 + kn, &Bl[p ^ 1][woff]);
      async16(B1 + kn, &Bl[p ^ 1][2048 + woff]);
    }
    int spos = (q ^ (l16 & 3)) * 8;   // swizzled read position
    short8 af[MTILES], bfr[4];
#pragma unroll
    for (int i4 = 0; i4 < MTILES; ++i4)
      af[i4] = *(const short8*)(&Al[p][(rw + i4 * 16 + l16) * 32 + spos]);
#pragma unroll
    for (int i4 = 0; i4 < 4; ++i4)
      bfr[i4] = *(const short8*)(&Bl[p][(cw + i4 * 16 + l16) * 32 + spos]);
#pragma unroll
    for (int mt = 0; mt < MTILES; ++mt)
#pragma unroll
      for (int nt = 0; nt < 4; ++nt)
        acc[mt][nt] = __builtin_amdgcn_mfma_f32_16x16x32_bf16(af[mt], bfr[nt], acc[mt][nt], 0, 0, 0);
    p ^= 1;
  }
  // epilogue: D[row = q*4 + r][col = lane&15] per 16x16 tile (verified mapping)
  int isv = uv_mode && (n0 >= 2048);
  int ldc = uv_mode ? 2048 : N;
  int ncb = isv ? (n0 - 2048) : n0;
  const float* buse = isv ? bias2 : bias;
#pragma unroll
  for (int mt = 0; mt < MTILES; ++mt) {
#pragma unroll
    for (int nt = 0; nt < 4; ++nt) {
      int n = ncb + cw + nt * 16 + l16;
      float bsv = buse[n];
#pragma unroll
      for (int r = 0; r < 4; ++r) {
        int m = m0 + rw + mt * 16 + q * 4 + r;
        float val = acc[mt][nt][r] + bsv;
        if (do_silu) val = val / (1.0f + __expf(-val));
        if (isv) {
          size_t mrow = (size_t)(2048 + m + ((m >> 11) << 12));  // padded-V row
          ((unsigned short*)C2)[mrow * 2048 + n] = f2bf(val);
        } else if (c_fp32) {
          ((float*)C)[(size_t)m * ldc + n] = val;
        } else {
          ((unsigned short*)C)[(size_t)m * ldc + n] = f2bf(val);
        }
      }
    }
  }
}

// ---------------- chunked IIR scan (phase A) -------------------------------
// Per (dir, b, chunk, c-pair): zero-state local scan of CLEN steps.
//   F[t] = sum_j delta[h,j,d] * Vp[b, 2048 + t -/+ l_j, c]   (pads are zero)
// delta staged in LDS as fp32 (precision-critical); lag taps reuse lead
// values from the previous step via register carries: 15 V-loads/step not 28.
__global__ __launch_bounds__(256) void scan_chunks(const unsigned short* __restrict__ Vp,
                                                   const float* __restrict__ dp,
                                                   const float* __restrict__ dn,
                                                   unsigned short* __restrict__ ypl,
                                                   unsigned short* __restrict__ ynl,
                                                   float* __restrict__ Sy_ex,
                                                   float* __restrict__ SG_ex) {
  __shared__ float dsh[NTAP][512];   // 57344 B: fp32 delta for 512 channels
  int z = blockIdx.z;            // dir*2 + b
  int dir = z >> 1, b = z & 1;
  int chunk = blockIdx.y;
  int cBase = blockIdx.x * 512;
  int tid = threadIdx.x;
  {
    const float* dt = dir ? dn : dp;
    for (int e = tid; e < NTAP * 512; e += 256) {
      int j = e >> 9, cl = e & 511;
      int c = cBase + cl, h = c >> 7, d = c & 127;
      dsh[j][cl] = dt[((size_t)h * NTAP + j) * HD + d];
    }
  }
  __syncthreads();
  int c0 = cBase + tid * 2;      // two channels per thread
  int cl0 = tid * 2;
  const unsigned short* Vb = Vp + (size_t)b * VPROWS * D1 + c0;
  unsigned short* yl = (dir ? ynl : ypl) + (size_t)b * NSEQ * D1 + c0;
  float sy0 = 0.f, sy1 = 0.f, sg0 = 0.f, sg1 = 0.f;
  float carry0[NPAIR], carry1[NPAIR];
  if (!dir) {
    int t0 = chunk * CLEN;
    const unsigned short* Vrow = Vb + (size_t)(2048 + t0) * D1;
    // prime carries with step -1 lead values: row t0-1-l  (pad rows are zero)
#pragma unroll
    for (int p = 0; p < NPAIR; ++p) {
      unsigned int pk = *(const unsigned int*)(Vrow - (ptrdiff_t)(LEADL[p] + 1) * D1);
      carry0[p] = bflo(pk); carry1[p] = bfhi(pk);
    }
    int t = t0;
    for (int i = 0; i < CLEN; ++i) {
      float F0 = 0.f, F1 = 0.f;
#pragma unroll
      for (int p = 0; p < NPAIR; ++p) {
        unsigned int pk = *(const unsigned int*)(Vrow - (ptrdiff_t)LEADL[p] * D1);
        float vl0 = bflo(pk), vl1 = bfhi(pk);
        float2 dl = *(const float2*)&dsh[LEADI[p]][cl0];
        float2 dg = *(const float2*)&dsh[LEADI[p] + 1][cl0];
        F0 += dl.x * vl0 + dg.x * carry0[p];
        F1 += dl.y * vl1 + dg.y * carry1[p];
        carry0[p] = vl0; carry1[p] = vl1;
      }
      {
        unsigned int pk = *(const unsigned int*)(Vrow - (ptrdiff_t)SGL0_L * D1);
        float2 ds = *(const float2*)&dsh[SGL0_I][cl0];
        F0 += ds.x * bflo(pk); F1 += ds.y * bfhi(pk);
      }
      {
        unsigned int pk = *(const unsigned int*)(Vrow - (ptrdiff_t)SGL1_L * D1);
        float2 ds = *(const float2*)&dsh[SGL1_I][cl0];
        F0 += ds.x * bflo(pk); F1 += ds.y * bfhi(pk);
      }
      sg0 = GAMMA_F * sg0 + F0; sy0 = GAMMA_F * sy0 + sg0;
      sg1 = GAMMA_F * sg1 + F1; sy1 = GAMMA_F * sy1 + sg1;
      unsigned int pack = (unsigned int)f2bf(sy0) | ((unsigned int)f2bf(sy1) << 16);
      *(unsigned int*)(yl + (size_t)(t + i) * D1) = pack;
      Vrow += D1;
    }
  } else {
    int tstart = (NSEQ - 1) - chunk * CLEN;        // reversed time
    const unsigned short* Vrow = Vb + (size_t)(2048 + tstart) * D1;
#pragma unroll
    for (int p = 0; p < NPAIR; ++p) {
      unsigned int pk = *(const unsigned int*)(Vrow + (ptrdiff_t)(LEADL[p] + 1) * D1);
      carry0[p] = bflo(pk); carry1[p] = bfhi(pk);
    }
    for (int i = 0; i < CLEN; ++i) {
      float F0 = 0.f, F1 = 0.f;
#pragma unroll
      for (int p = 0; p < NPAIR; ++p) {
        unsigned int pk = *(const unsigned int*)(Vrow + (ptrdiff_t)LEADL[p] * D1);
        float vl0 = bflo(pk), vl1 = bfhi(pk);
        float2 dl = *(const float2*)&dsh[LEADI[p]][cl0];
        float2 dg = *(const float2*)&dsh[LEADI[p] + 1][cl0];
        F0 += dl.x * vl0 + dg.x * carry0[p];
        F1 += dl.y * vl1 + dg.y * carry1[p];
        carry0[p] = vl0; carry1[p] = vl1;
      }
      {
        unsigned int pk = *(const unsigned int*)(Vrow + (ptrdiff_t)SGL0_L * D1);
        float2 ds = *(const float2*)&dsh[SGL0_I][cl0];
        F0 += ds.x * bflo(pk); F1 += ds.y * bfhi(pk);
      }
      {
        unsigned int pk = *(const unsigned int*)(Vrow + (ptrdiff_t)SGL1_L * D1);
        float2 ds = *(const float2*)&dsh[SGL1_I][cl0];
        F0 += ds.x * bflo(pk); F1 += ds.y * bfhi(pk);
      }
      sg0 = GAMMA_F * sg0 + F0; sy0 = GAMMA_F * sy0 + sg0;
      sg1 = GAMMA_F * sg1 + F1; sy1 = GAMMA_F * sy1 + sg1;
      unsigned int pack = (unsigned int)f2bf(sy0) | ((unsigned int)f2bf(sy1) << 16);
      *(unsigned int*)(yl + (size_t)(tstart - i) * D1) = pack;
      Vrow -= D1;
    }
  }
  size_t sidx = ((size_t)z * NCHUNK + chunk) * D1 + c0;
  Sy_ex[sidx] = sy0; Sy_ex[sidx + 1] = sy1;
  SG_ex[sidx] = sg0; SG_ex[sidx + 1] = sg1;
}

// ---------------- chunk-state scan (phase B) -------------------------------
// entry(k+1) = local_exit(k) + homogeneous fixup from entry(k), L = CLEN.
__global__ __launch_bounds__(256) void state_scan(const float* __restrict__ Sy_ex,
                                                  const float* __restrict__ SG_ex,
                                                  float* __restrict__ Sy_in,
                                                  float* __restrict__ SG_in) {
  int idx = blockIdx.x * 256 + threadIdx.x;   // z*2048 + c, total 4*2048
  if (idx >= 4 * D1) return;
  int z = idx >> 11, c = idx & (D1 - 1);
  float ey = 0.f, eg = 0.f;
  for (int k = 0; k < NCHUNK; ++k) {
    size_t s = ((size_t)z * NCHUNK + k) * D1 + c;
    Sy_in[s] = ey; SG_in[s] = eg;
    float lex = Sy_ex[s], lgx = SG_ex[s];
    ey = lex + G_CL * (ey + (float)CLEN * eg);
    eg = lgx + G_CL * eg;
  }
}

// ---------------- combine + gate (phase C), 4 channels/thread --------------
// y = [y+loc + g^Dp (y_in + Dp G_in)] + [y-loc + g^Dn (...)] + tz*V;  g = U*y
__global__ __launch_bounds__(256) void combine_kernel(const unsigned short* __restrict__ ypl,
                                                      const unsigned short* __restrict__ ynl,
                                                      const unsigned short* __restrict__ Vp,
                                                      const float* __restrict__ Sy_in,
                                                      const float* __restrict__ SG_in,
                                                      const float* __restrict__ tz,
                                                      const unsigned short* __restrict__ U,
                                                      unsigned short* __restrict__ G) {
  int e = blockIdx.x * 256 + threadIdx.x;     // quad index over [b][t][c/4]
  int cq = e & (D1 / 4 - 1);
  int c0 = cq * 4;
  int r = e >> 9;
  int t = r & (NSEQ - 1);
  int b = r >> 11;
  int kp = t >> 5;  float dpD = (float)((t & 31) + 1);
  int tau = (NSEQ - 1) - t;
  int kn = tau >> 5; float dnD = (float)((tau & 31) + 1);
  float gp = __expf(dpD * LN_G);
  float gn = __expf(dnD * LN_G);
  size_t ix = (size_t)r * D1 + c0;
  size_t sp = ((size_t)(b) * NCHUNK + kp) * D1 + c0;          // z = b (pos)
  size_t sn = ((size_t)(2 + b) * NCHUNK + kn) * D1 + c0;      // z = 2+b (neg)
  uint2 pyl = *(const uint2*)(ypl + ix);
  uint2 pyn = *(const uint2*)(ynl + ix);
  uint2 pv  = *(const uint2*)(Vp + ((size_t)b * VPROWS + 2048 + t) * D1 + c0);
  uint2 pu  = *(const uint2*)(U + ix);
  float4 syp = *(const float4*)(Sy_in + sp);
  float4 sgp = *(const float4*)(SG_in + sp);
  float4 syn = *(const float4*)(Sy_in + sn);
  float4 sgn = *(const float4*)(SG_in + sn);
  float4 tzv = *(const float4*)(tz + c0);
  float yv[4], uv[4], vv[4];
  yv[0] = bflo(pyl.x) + gp * (syp.x + dpD * sgp.x) + bflo(pyn.x) + gn * (syn.x + dnD * sgn.x);
  yv[1] = bfhi(pyl.x) + gp * (syp.y + dpD * sgp.y) + bfhi(pyn.x) + gn * (syn.y + dnD * sgn.y);
  yv[2] = bflo(pyl.y) + gp * (syp.z + dpD * sgp.z) + bflo(pyn.y) + gn * (syn.z + dnD * sgn.z);
  yv[3] = bfhi(pyl.y) + gp * (syp.w + dpD * sgp.w) + bfhi(pyn.y) + gn * (syn.w + dnD * sgn.w);
  vv[0] = bflo(pv.x); vv[1] = bfhi(pv.x); vv[2] = bflo(pv.y); vv[3] = bfhi(pv.y);
  uv[0] = bflo(pu.x); uv[1] = bfhi(pu.x); uv[2] = bflo(pu.y); uv[3] = bfhi(pu.y);
  float tza[4] = {tzv.x, tzv.y, tzv.z, tzv.w};
  uint2 og;
  unsigned short g0 = f2bf(uv[0] * (yv[0] + tza[0] * vv[0]));
  unsigned short g1 = f2bf(uv[1] * (yv[1] + tza[1] * vv[1]));
  unsigned short g2 = f2bf(uv[2] * (yv[2] + tza[2] * vv[2]));
  unsigned short g3 = f2bf(uv[3] * (yv[3] + tza[3] * vv[3]));
  og.x = (unsigned int)g0 | ((unsigned int)g1 << 16);
  og.y = (unsigned int)g2 | ((unsigned int)g3 << 16);
  *(uint2*)(G + ix) = og;
}

// ---------------------------------------------------------------------------
extern "C" void kernel_launch(void* const* d_in, const int* in_sizes, int n_in,
                              void* d_out, int out_size, void* d_ws, size_t ws_size,
                              hipStream_t stream) {
  const float* x      = (const float*)d_in[0];
  const float* Wu     = (const float*)d_in[1];
  const float* bu     = (const float*)d_in[2];
  const float* Wv     = (const float*)d_in[3];
  const float* bv     = (const float*)d_in[4];
  const float* Wo     = (const float*)d_in[5];
  const float* bo     = (const float*)d_in[6];
  const float* a_pos  = (const float*)d_in[7];
  const float* b_pos  = (const float*)d_in[8];
  const float* a_neg  = (const float*)d_in[9];
  const float* b_neg  = (const float*)d_in[10];
  const float* t_zero = (const float*)d_in[11];
  float* out = (float*)d_out;

  char* ws = (char*)d_ws;
  unsigned short* x_bf  = (unsigned short*)ws; ws += (size_t)MROWS * DM * 2;        //  8 MB
  unsigned short* u_ws  = (unsigned short*)ws; ws += (size_t)MROWS * D1 * 2;        // 16 MB (g in-place)
  unsigned short* Vp    = (unsigned short*)ws; ws += (size_t)BB * VPROWS * D1 * 2;  // 48 MB padded V
  unsigned short* ypl   = (unsigned short*)ws; ws += (size_t)MROWS * D1 * 2;        // 16 MB
  unsigned short* ynl   = (unsigned short*)ws; ws += (size_t)MROWS * D1 * 2;        // 16 MB
  float* dtp   = (float*)ws; ws += (size_t)H * NTAP * HD * 4;                       // 229 KB (fp32!)
  float* dtn   = (float*)ws; ws += (size_t)H * NTAP * HD * 4;
  float* Sy_ex = (float*)ws; ws += (size_t)4 * NCHUNK * D1 * 4;                     // 2 MB each
  float* SG_ex = (float*)ws; ws += (size_t)4 * NCHUNK * D1 * 4;
  float* Sy_in = (float*)ws; ws += (size_t)4 * NCHUNK * D1 * 4;
  float* SG_in = (float*)ws; ws += (size_t)4 * NCHUNK * D1 * 4;
  // weight buffers alias ypl (disjoint lifetimes, stream-ordered)
  unsigned short* WT2 = ypl;
  unsigned short* WoT = ypl;

  dim3 tb256(256);
  dim3 tptb(32, 8);
  // zero the V pads (rows [0,2048) and [4096,6144) per b)
  (void)hipMemsetAsync(Vp, 0, (size_t)2048 * D1 * 2, stream);
  (void)hipMemsetAsync(Vp + (size_t)4096 * D1, 0, (size_t)2048 * D1 * 2, stream);
  (void)hipMemsetAsync(Vp + (size_t)VPROWS * D1, 0, (size_t)2048 * D1 * 2, stream);
  (void)hipMemsetAsync(Vp + ((size_t)VPROWS + 4096) * D1, 0, (size_t)2048 * D1 * 2, stream);
  // x -> bf16
  cvt_kernel<<<dim3((MROWS * DM / 4 + 255) / 256), tb256, 0, stream>>>(x, x_bf, MROWS * DM / 4);
  // low-rank kernel factors -> sparse fp32 delta tables (fused, both dirs)
  kdtab_kernel<<<dim3(H, 2), tb256, 0, stream>>>(a_pos, b_pos, a_neg, b_neg, dtp, dtn);
  // fused u|v gemm: Bt = [WuT ; WvT]  (N = 4096), 128x128 tiles
  tpc_kernel<<<dim3(D1 / 32, DM / 32), tptb, 0, stream>>>(Wu, WT2, DM, D1);
  tpc_kernel<<<dim3(D1 / 32, DM / 32), tptb, 0, stream>>>(Wv, WT2 + (size_t)D1 * DM, DM, D1);
  gemm_bf16<4><<<dim3(2 * D1 / 128, MROWS / 128), tb256, 0, stream>>>(
      x_bf, WT2, bu, bv, u_ws, Vp, MROWS, 2 * D1, DM, 1, 0, 1);
  // IIR conv: chunked scans -> state scan -> combine+gate (in-place over u)
  scan_chunks<<<dim3(D1 / 512, NCHUNK, 4), tb256, 0, stream>>>(Vp, dtp, dtn, ypl, ynl, Sy_ex, SG_ex);
  state_scan<<<dim3((4 * D1 + 255) / 256), tb256, 0, stream>>>(Sy_ex, SG_ex, Sy_in, SG_in);
  combine_kernel<<<dim3((size_t)MROWS * D1 / 1024), tb256, 0, stream>>>(ypl, ynl, Vp, Sy_in, SG_in, t_zero, u_ws, u_ws);
  // out = g @ Wo + bo (fp32), 64x128 tiles -> 512 blocks = 2/CU
  tpc_kernel<<<dim3(DM / 32, D1 / 32), tptb, 0, stream>>>(Wo, WoT, D1, DM);
  gemm_bf16<2><<<dim3(DM / 128, MROWS / 64), tb256, 0, stream>>>(
      u_ws, WoT, bo, bo, out, out, MROWS, DM, D1, 0, 1, 0);
}